// Round 3
// baseline (1999.377 us; speedup 1.0000x reference)
//
#include <hip/hip_runtime.h>
#include <math.h>

// ---------------------------------------------------------------------------
// MLA transformer block. B=2, T=2048, C=1024, NH=16, HD=64, DHR=32, L=512.
// M = B*T = 4096 rows.
//
// GEMMs run on bf16 MFMA with 2-term error-compensated split:
//   A = Ah + Al (bf16 each), W = Wh + Wl;  A@W ~= Ah Wh + Ah Wl + Al Wh
// (~1e-4 rel error, fp32-faithful for typical tolerances) at 3x bf16 cost.
// Weight splits are precomputed once per launch into packed u32 (hi|lo<<16).
//
// Workspace layout (floats, 1MF = 1<<20 elements):
//   xn   @ 0    (4MF)  : rmsnorm output (reused for xn2)
//   hb   @ 4MF  (4MF)  : h = xn@w1+b1   (later: att output, ffh start)
//   kvb  @ 8MF  (8MF)  : kv                     [4096 x 2048]
//   qb   @ 16MF (4MF)  : q                      [4096 x 1024]
//   qrb  @ 20MF (2MF)  : qr (rope'd)            [4096 x 512]
//   krb  @ 22MF (128K) : kr (rope'd)            [4096 x 32]
//   ffh  = hb.. (16MF) : gelu(xn2@wi+bi)        [4096 x 4096]
//   packed weights @ 23MF.. (u32): w1p(1M) wkrp wqrp wkvp wqp wop wip(4M) wo2p(4M)
// Total = 37MF * 4B = 148 MB.
// ---------------------------------------------------------------------------

typedef __attribute__((ext_vector_type(8))) __bf16 bf16x8;
typedef __attribute__((ext_vector_type(4))) float f32x4;

// ------------------- weight hi/lo split precompute --------------------------
__global__ __launch_bounds__(256) void split_pack_kernel(
    const float* __restrict__ w, unsigned int* __restrict__ wp, int n4)
{
    int i = blockIdx.x * 256 + threadIdx.x;
    const int stride = gridDim.x * 256;
    for (; i < n4; i += stride) {
        const float4 v = ((const float4*)w)[i];
        uint4 o;
        const float vv[4] = {v.x, v.y, v.z, v.w};
        unsigned int ov[4];
        #pragma unroll
        for (int j = 0; j < 4; ++j) {
            const float xv = vv[j];
            const __bf16 h = (__bf16)xv;
            const __bf16 l = (__bf16)(xv - (float)h);
            ov[j] = (unsigned int)__builtin_bit_cast(unsigned short, h)
                  | ((unsigned int)__builtin_bit_cast(unsigned short, l) << 16);
        }
        o.x = ov[0]; o.y = ov[1]; o.z = ov[2]; o.w = ov[3];
        ((uint4*)wp)[i] = o;
    }
}

// ---------------------------- RMSNorm --------------------------------------
__global__ __launch_bounds__(256) void rmsnorm_kernel(
    const float* __restrict__ x, const float* __restrict__ g,
    float* __restrict__ out)
{
    __shared__ float sm[4];
    const int row = blockIdx.x;
    const int tid = threadIdx.x;
    float4 v = ((const float4*)(x + (size_t)row * 1024))[tid];
    float ss = v.x * v.x + v.y * v.y + v.z * v.z + v.w * v.w;
    #pragma unroll
    for (int m = 32; m; m >>= 1) ss += __shfl_xor(ss, m, 64);
    if ((tid & 63) == 0) sm[tid >> 6] = ss;
    __syncthreads();
    const float total = sm[0] + sm[1] + sm[2] + sm[3];
    const float rstd = rsqrtf(total * (1.0f / 1024.0f) + 1e-6f);
    float4 gv = ((const float4*)g)[tid];
    float4 o;
    o.x = v.x * rstd * gv.x;
    o.y = v.y * rstd * gv.y;
    o.z = v.z * rstd * gv.z;
    o.w = v.w * rstd * gv.w;
    ((float4*)(out + (size_t)row * 1024))[tid] = o;
}

// ------------------------ MFMA split-bf16 GEMM ------------------------------
// C[M,N] = act(A[M,K] @ W[K,N] + bias) (+ res).  Tile 128x128, BK=64.
// 4 waves, each owns a 64x64 quadrant = 4x4 fragments of 16x16.
// LDS tiles [row][64 bf16] with 16B-slot XOR swizzle (slot ^= row&7).
__global__ __launch_bounds__(256, 2) void gemm_mfma_kernel(
    const float* __restrict__ A, int lda,
    const unsigned int* __restrict__ Wp,     // packed hi|lo<<16, [K][N]
    const float* __restrict__ bias,
    const float* __restrict__ res, int ldres,
    float* __restrict__ C, int ldc,
    int N, int K, int act)
{
    __shared__ __bf16 Ah[128 * 64];
    __shared__ __bf16 Al[128 * 64];
    __shared__ __bf16 Bh[128 * 64];
    __shared__ __bf16 Bl[128 * 64];

    const int tid = threadIdx.x;
    const int m0 = blockIdx.y * 128;
    const int n0 = blockIdx.x * 128;
    const int lane = tid & 63;
    const int w = tid >> 6;
    const int wm = (w >> 1) * 64;
    const int wn = (w & 1) * 64;

    f32x4 acc[4][4];
    #pragma unroll
    for (int i = 0; i < 4; ++i)
        #pragma unroll
        for (int j = 0; j < 4; ++j) acc[i][j] = (f32x4){0.f, 0.f, 0.f, 0.f};

    const int ar = tid >> 1;           // A staging row 0..127
    const int ak = (tid & 1) * 32;     // A k-offset
    const int bc = tid & 127;          // B staging col 0..127
    const int bk = (tid >> 7) * 32;    // B k-offset 0/32
    const int bcol = n0 + bc;
    const bool bok = bcol < N;

    for (int k0 = 0; k0 < K; k0 += 64) {
        __syncthreads();
        // ---- stage A (fp32 -> bf16 hi/lo), row-contiguous loads ----
        {
            const float* src = A + (size_t)(m0 + ar) * lda + k0 + ak;
            float va[32];
            #pragma unroll
            for (int i = 0; i < 8; ++i) {
                float4 v = ((const float4*)src)[i];
                va[i * 4 + 0] = v.x; va[i * 4 + 1] = v.y;
                va[i * 4 + 2] = v.z; va[i * 4 + 3] = v.w;
            }
            #pragma unroll
            for (int s = 0; s < 4; ++s) {
                const int slot = (ak >> 3) + s;
                const int swz = slot ^ (ar & 7);
                bf16x8 hh, ll;
                #pragma unroll
                for (int j = 0; j < 8; ++j) {
                    const float xv = va[s * 8 + j];
                    const __bf16 h = (__bf16)xv;
                    hh[j] = h;
                    ll[j] = (__bf16)(xv - (float)h);
                }
                *(bf16x8*)&Ah[ar * 64 + swz * 8] = hh;
                *(bf16x8*)&Al[ar * 64 + swz * 8] = ll;
            }
        }
        // ---- stage B from packed weights (coalesced dword loads) ----
        {
            const unsigned int* src = Wp + (size_t)(k0 + bk) * N + bcol;
            unsigned int up[32];
            #pragma unroll
            for (int j = 0; j < 32; ++j)
                up[j] = bok ? src[(size_t)j * N] : 0u;
            #pragma unroll
            for (int s = 0; s < 4; ++s) {
                const int slot = (bk >> 3) + s;
                const int swz = slot ^ (bc & 7);
                bf16x8 hh, ll;
                #pragma unroll
                for (int j = 0; j < 8; ++j) {
                    const unsigned int p = up[s * 8 + j];
                    hh[j] = __builtin_bit_cast(__bf16, (unsigned short)(p & 0xffffu));
                    ll[j] = __builtin_bit_cast(__bf16, (unsigned short)(p >> 16));
                }
                *(bf16x8*)&Bh[bc * 64 + swz * 8] = hh;
                *(bf16x8*)&Bl[bc * 64 + swz * 8] = ll;
            }
        }
        __syncthreads();

        #pragma unroll
        for (int kc = 0; kc < 2; ++kc) {
            bf16x8 fAh[4], fAl[4], fBh[4], fBl[4];
            #pragma unroll
            for (int i = 0; i < 4; ++i) {
                const int row = wm + i * 16 + (lane & 15);
                const int slot = kc * 4 + (lane >> 4);
                const int offa = row * 64 + (slot ^ (row & 7)) * 8;
                fAh[i] = *(const bf16x8*)&Ah[offa];
                fAl[i] = *(const bf16x8*)&Al[offa];
                const int col = wn + i * 16 + (lane & 15);
                const int offb = col * 64 + (slot ^ (col & 7)) * 8;
                fBh[i] = *(const bf16x8*)&Bh[offb];
                fBl[i] = *(const bf16x8*)&Bl[offb];
            }
            #pragma unroll
            for (int i = 0; i < 4; ++i)
                #pragma unroll
                for (int j = 0; j < 4; ++j) {
                    acc[i][j] = __builtin_amdgcn_mfma_f32_16x16x32_bf16(
                        fAl[i], fBh[j], acc[i][j], 0, 0, 0);
                    acc[i][j] = __builtin_amdgcn_mfma_f32_16x16x32_bf16(
                        fAh[i], fBl[j], acc[i][j], 0, 0, 0);
                    acc[i][j] = __builtin_amdgcn_mfma_f32_16x16x32_bf16(
                        fAh[i], fBh[j], acc[i][j], 0, 0, 0);
                }
        }
    }

    // ---- epilogue: C/D layout col=lane&15, row=(lane>>4)*4+r ----
    const int rb = (lane >> 4) * 4;
    const int cc = lane & 15;
    #pragma unroll
    for (int j = 0; j < 4; ++j) {
        const int col = n0 + wn + j * 16 + cc;
        if (col >= N) continue;
        const float bv = bias[col];
        #pragma unroll
        for (int i = 0; i < 4; ++i) {
            #pragma unroll
            for (int r = 0; r < 4; ++r) {
                const int row = m0 + wm + i * 16 + rb + r;
                float v = acc[i][j][r] + bv;
                if (act == 1) {
                    const float t = 0.7978845608028654f * (v + 0.044715f * v * v * v);
                    v = 0.5f * v * (1.0f + tanhf(t));
                }
                if (res) v += res[(size_t)row * ldres + col];
                C[(size_t)row * ldc + col] = v;
            }
        }
    }
}

// ------------------------------- RoPE ---------------------------------------
// Matches reference numerics: angle = fp32((t+1) * theta_fp32), then accurate
// arg reduction of that fp32 value.
__global__ void rope_kernel(float* __restrict__ buf, int dim, int npairs)
{
    const int idx = blockIdx.x * blockDim.x + threadIdx.x;
    if (idx >= npairs) return;
    const int hp = dim >> 1;
    const int row = idx / hp;
    const int p = idx - row * hp;
    const int t = row & 2047;   // T = 2048
    const float theta = expf((float)p * (-2.0f / (float)dim) * 9.210340371976184f);
    const float pf = (float)(t + 1) * theta;          // fp32 product, like ref
    double ang = fmod((double)pf, 6.283185307179586476925286766559);
    const float c = (float)cos(ang);
    const float s = (float)sin(ang);
    float* pr = buf + (size_t)row * dim + 2 * p;
    const float x0 = pr[0], x1 = pr[1];
    pr[0] = x0 * c - x1 * s;
    pr[1] = x1 * c + x0 * s;
}

// ------------------------ flash causal attention ----------------------------
// dk = 96 (64 nope + 32 rope), dv = 64. Grid (T/32, NH, B), block 256.
__global__ __launch_bounds__(256) void attn_kernel(
    const float* __restrict__ q,    // [4096][1024]  head h at col h*64
    const float* __restrict__ qr,   // [4096][512]   head h at col h*32
    const float* __restrict__ kv,   // [4096][2048]  k at h*64, v at 1024+h*64
    const float* __restrict__ kr,   // [4096][32]    shared across heads
    float* __restrict__ att)        // [4096][1024]  head h at col h*64
{
    __shared__ float Qs[32][100];
    __shared__ float Ks[32][100];
    __shared__ float Vs[32][68];
    __shared__ float Ss[32][33];
    __shared__ float mrow[32], lrow[32], rsc[32];

    const int qt = blockIdx.x, h = blockIdx.y, b = blockIdx.z;
    const int tid = threadIdx.x;
    const float scale = 0.10206207261596575f;  // 1/sqrt(96)
    const int rowQ0 = b * 2048 + qt * 32;
    const int rowK0 = b * 2048;

    #pragma unroll
    for (int i = 0; i < 12; ++i) {
        const int idx = tid + i * 256;
        const int r = idx / 96, col = idx - r * 96;
        const int grow = rowQ0 + r;
        const float v = (col < 64) ? q[grow * 1024 + h * 64 + col]
                                   : qr[grow * 512 + h * 32 + (col - 64)];
        Qs[r][col] = v * scale;
    }
    if (tid < 32) { mrow[tid] = -1e30f; lrow[tid] = 0.f; }

    const int r_s = tid >> 3;          // score row 0..31 (also softmax row)
    const int cb  = tid & 7;           // score col base; cols = cb + 8j
    const int r_a = tid & 31;          // acc row
    const int d0  = (tid >> 5) << 3;   // acc dim base (8 dims)
    float acc[8] = {0.f, 0.f, 0.f, 0.f, 0.f, 0.f, 0.f, 0.f};

    for (int kt = 0; kt <= qt; ++kt) {
        __syncthreads();
        #pragma unroll
        for (int i = 0; i < 12; ++i) {
            const int idx = tid + i * 256;
            const int r = idx / 96, col = idx - r * 96;
            const int grow = rowK0 + kt * 32 + r;
            Ks[r][col] = (col < 64) ? kv[grow * 2048 + h * 64 + col]
                                    : kr[grow * 32 + (col - 64)];
        }
        #pragma unroll
        for (int i = 0; i < 8; ++i) {
            const int idx = tid + i * 256;
            const int r = idx >> 6, col = idx & 63;
            const int grow = rowK0 + kt * 32 + r;
            Vs[r][col] = kv[grow * 2048 + 1024 + h * 64 + col];
        }
        __syncthreads();

        float s[4] = {0.f, 0.f, 0.f, 0.f};
        for (int k4 = 0; k4 < 96; k4 += 4) {
            const float4 qv = *(const float4*)&Qs[r_s][k4];
            #pragma unroll
            for (int j = 0; j < 4; ++j) {
                const float4 kw = *(const float4*)&Ks[cb + 8 * j][k4];
                s[j] += qv.x * kw.x + qv.y * kw.y + qv.z * kw.z + qv.w * kw.w;
            }
        }
        if (kt == qt) {
            const int gq = qt * 32 + r_s;
            #pragma unroll
            for (int j = 0; j < 4; ++j)
                if (kt * 32 + cb + 8 * j > gq) s[j] = -1e30f;
        }

        // ---- parallel online softmax: 8 lanes per row ----
        const float mold = mrow[r_s];
        float mx = fmaxf(fmaxf(s[0], s[1]), fmaxf(s[2], s[3]));
        mx = fmaxf(mx, mold);
        #pragma unroll
        for (int m = 1; m < 8; m <<= 1) mx = fmaxf(mx, __shfl_xor(mx, m, 64));
        float sum = 0.f;
        #pragma unroll
        for (int j = 0; j < 4; ++j) {
            const float pv = expf(s[j] - mx);
            Ss[r_s][cb + 8 * j] = pv;
            sum += pv;
        }
        #pragma unroll
        for (int m = 1; m < 8; m <<= 1) sum += __shfl_xor(sum, m, 64);
        if (cb == 0) {
            const float rs = expf(mold - mx);
            rsc[r_s] = rs;
            lrow[r_s] = lrow[r_s] * rs + sum;
            mrow[r_s] = mx;
        }
        __syncthreads();

        const float rs = rsc[r_a];
        #pragma unroll
        for (int d = 0; d < 8; ++d) acc[d] *= rs;
        for (int c = 0; c < 32; ++c) {
            const float p = Ss[r_a][c];
            const float4 v0 = *(const float4*)&Vs[c][d0];
            const float4 v1 = *(const float4*)&Vs[c][d0 + 4];
            acc[0] += p * v0.x; acc[1] += p * v0.y;
            acc[2] += p * v0.z; acc[3] += p * v0.w;
            acc[4] += p * v1.x; acc[5] += p * v1.y;
            acc[6] += p * v1.z; acc[7] += p * v1.w;
        }
    }

    const float linv = 1.0f / lrow[r_a];
    const int grow = rowQ0 + r_a;
    #pragma unroll
    for (int d = 0; d < 8; ++d)
        att[grow * 1024 + h * 64 + d0 + d] = acc[d] * linv;
}

static inline void gemm(hipStream_t s, const float* A, int lda,
                        const unsigned int* Wp,
                        const float* bias, const float* res, int ldres,
                        float* C, int ldc, int M, int N, int K, int act)
{
    dim3 grid((N + 127) / 128, M / 128);
    gemm_mfma_kernel<<<grid, 256, 0, s>>>(A, lda, Wp, bias, res, ldres,
                                          C, ldc, N, K, act);
}

static inline void split_pack(hipStream_t s, const float* w, unsigned int* wp, int n)
{
    const int n4 = n >> 2;
    const int blocks = (n4 + 255) / 256 < 2048 ? (n4 + 255) / 256 : 2048;
    split_pack_kernel<<<blocks, 256, 0, s>>>(w, wp, n4);
}

extern "C" void kernel_launch(void* const* d_in, const int* in_sizes, int n_in,
                              void* d_out, int out_size, void* d_ws, size_t ws_size,
                              hipStream_t stream)
{
    const float* x   = (const float*)d_in[0];
    const float* w1  = (const float*)d_in[1];
    const float* b1  = (const float*)d_in[2];
    const float* wkr = (const float*)d_in[3];
    const float* bkr = (const float*)d_in[4];
    const float* wqr = (const float*)d_in[5];
    const float* bqr = (const float*)d_in[6];
    const float* wkv = (const float*)d_in[7];
    const float* bkv = (const float*)d_in[8];
    const float* wq  = (const float*)d_in[9];
    const float* bq  = (const float*)d_in[10];
    const float* wo  = (const float*)d_in[11];
    const float* bo  = (const float*)d_in[12];
    const float* wi  = (const float*)d_in[13];
    const float* bi  = (const float*)d_in[14];
    const float* wo2 = (const float*)d_in[15];
    const float* bo2 = (const float*)d_in[16];
    const float* g1  = (const float*)d_in[17];
    const float* g2  = (const float*)d_in[18];
    float* out = (float*)d_out;
    float* ws  = (float*)d_ws;

    const size_t MF = (size_t)1 << 20;
    float* xn  = ws;              // 4MF, reused as xn2
    float* hb  = ws + 4 * MF;     // 4MF
    float* kvb = ws + 8 * MF;     // 8MF
    float* qb  = ws + 16 * MF;    // 4MF
    float* qrb = ws + 20 * MF;    // 2MF
    float* krb = ws + 22 * MF;    // 128K floats
    float* attb = hb;
    float* ffh  = hb;             // 16MF spanning hb,kvb,qb (all dead by then)
    unsigned int* w1p  = (unsigned int*)(ws + 23 * MF);  // 1M
    unsigned int* wkrp = (unsigned int*)(ws + 24 * MF);  // 32K
    unsigned int* wqrp = (unsigned int*)(ws + 25 * MF);  // 512K
    unsigned int* wkvp = (unsigned int*)(ws + 26 * MF);  // 1M
    unsigned int* wqp  = (unsigned int*)(ws + 27 * MF);  // 512K
    unsigned int* wop  = (unsigned int*)(ws + 28 * MF);  // 1M
    unsigned int* wip  = (unsigned int*)(ws + 29 * MF);  // 4M
    unsigned int* wo2p = (unsigned int*)(ws + 33 * MF);  // 4M  -> total 37MF

    // ---- weight split precompute (every launch; ws is re-poisoned) ----
    split_pack(stream, w1,  w1p,  1024 * 1024);
    split_pack(stream, wkr, wkrp, 1024 * 32);
    split_pack(stream, wqr, wqrp, 1024 * 512);
    split_pack(stream, wkv, wkvp, 512 * 2048);
    split_pack(stream, wq,  wqp,  512 * 1024);
    split_pack(stream, wo,  wop,  1024 * 1024);
    split_pack(stream, wi,  wip,  1024 * 4096);
    split_pack(stream, wo2, wo2p, 4096 * 1024);

    // ---- attention branch ----
    rmsnorm_kernel<<<4096, 256, 0, stream>>>(x, g1, xn);
    gemm(stream, xn, 1024, w1p, b1, nullptr, 0, hb, 1024, 4096, 1024, 1024, 0);
    gemm(stream, hb, 1024, wkrp, bkr, nullptr, 0, krb, 32, 4096, 32, 1024, 0);
    gemm(stream, hb, 1024, wqrp, bqr, nullptr, 0, qrb, 512, 4096, 512, 1024, 0);
    gemm(stream, hb, 1024, wkvp, bkv, nullptr, 0, kvb, 2048, 4096, 2048, 512, 0);
    gemm(stream, hb + 512, 1024, wqp, bq, nullptr, 0, qb, 1024, 4096, 1024, 512, 0);
    rope_kernel<<<(4096 * 16 + 255) / 256, 256, 0, stream>>>(krb, 32, 4096 * 16);
    rope_kernel<<<(4096 * 256 + 255) / 256, 256, 0, stream>>>(qrb, 512, 4096 * 256);
    attn_kernel<<<dim3(64, 16, 2), 256, 0, stream>>>(qb, qrb, kvb, krb, attb);
    gemm(stream, attb, 1024, wop, bo, x, 1024, out, 1024, 4096, 1024, 1024, 0);

    // ---- FFN branch ----
    rmsnorm_kernel<<<4096, 256, 0, stream>>>(out, g2, xn);
    gemm(stream, xn, 1024, wip, bi, nullptr, 0, ffh, 4096, 4096, 4096, 1024, 1);
    gemm(stream, ffh, 4096, wo2p, bo2, out, 1024, out, 1024, 4096, 1024, 4096, 0);
}

// Round 5
// 1237.353 us; speedup vs baseline: 1.6159x; 1.6159x over previous
//
#include <hip/hip_runtime.h>
#include <math.h>

// ---------------------------------------------------------------------------
// MLA transformer block. B=2, T=2048, C=1024, NH=16, HD=64, DHR=32, L=512.
// M = B*T = 4096 rows.
//
// All matmuls (GEMMs and attention) on bf16 MFMA with 2-term split:
//   X = Xh + Xl (bf16 each);  X@Y ~= Xh Yh + Xh Yl + Xl Yh   (~1e-4 rel err)
// Attention: QK^T split x split (3 mfma), PV: P single bf16 x V split (2 mfma).
//
// Workspace layout (floats, 1MF = 1<<20 elements):
//   xn   @ 0    (4MF)  : rmsnorm output (reused for xn2)
//   hb   @ 4MF  (4MF)  : h = xn@w1+b1   (later: att output, ffh start)
//   kvb  @ 8MF  (8MF)  : kv                     [4096 x 2048]
//   qb   @ 16MF (4MF)  : q                      [4096 x 1024]
//   qrb  @ 20MF (2MF)  : qr (rope'd)            [4096 x 512]
//   krb  @ 22MF (128K) : kr (rope'd)            [4096 x 32]
//   ffh  = hb.. (16MF) : gelu(xn2@wi+bi)        [4096 x 4096]
//   packed weights @ 23MF.. (u32): w1p(1M) wkrp wqrp wkvp wqp wop wip(4M) wo2p(4M)
// Total = 37MF * 4B = 148 MB.
// ---------------------------------------------------------------------------

typedef __attribute__((ext_vector_type(8))) __bf16 bf16x8;
typedef __attribute__((ext_vector_type(4))) float f32x4;

// ------------------- weight hi/lo split precompute --------------------------
__global__ __launch_bounds__(256) void split_pack_kernel(
    const float* __restrict__ w, unsigned int* __restrict__ wp, int n4)
{
    int i = blockIdx.x * 256 + threadIdx.x;
    const int stride = gridDim.x * 256;
    for (; i < n4; i += stride) {
        const float4 v = ((const float4*)w)[i];
        uint4 o;
        const float vv[4] = {v.x, v.y, v.z, v.w};
        unsigned int ov[4];
        #pragma unroll
        for (int j = 0; j < 4; ++j) {
            const float xv = vv[j];
            const __bf16 h = (__bf16)xv;
            const __bf16 l = (__bf16)(xv - (float)h);
            ov[j] = (unsigned int)__builtin_bit_cast(unsigned short, h)
                  | ((unsigned int)__builtin_bit_cast(unsigned short, l) << 16);
        }
        o.x = ov[0]; o.y = ov[1]; o.z = ov[2]; o.w = ov[3];
        ((uint4*)wp)[i] = o;
    }
}

// ---------------------------- RMSNorm --------------------------------------
__global__ __launch_bounds__(256) void rmsnorm_kernel(
    const float* __restrict__ x, const float* __restrict__ g,
    float* __restrict__ out)
{
    __shared__ float sm[4];
    const int row = blockIdx.x;
    const int tid = threadIdx.x;
    float4 v = ((const float4*)(x + (size_t)row * 1024))[tid];
    float ss = v.x * v.x + v.y * v.y + v.z * v.z + v.w * v.w;
    #pragma unroll
    for (int m = 32; m; m >>= 1) ss += __shfl_xor(ss, m, 64);
    if ((tid & 63) == 0) sm[tid >> 6] = ss;
    __syncthreads();
    const float total = sm[0] + sm[1] + sm[2] + sm[3];
    const float rstd = rsqrtf(total * (1.0f / 1024.0f) + 1e-6f);
    float4 gv = ((const float4*)g)[tid];
    float4 o;
    o.x = v.x * rstd * gv.x;
    o.y = v.y * rstd * gv.y;
    o.z = v.z * rstd * gv.z;
    o.w = v.w * rstd * gv.w;
    ((float4*)(out + (size_t)row * 1024))[tid] = o;
}

// ------------------------ MFMA split-bf16 GEMM ------------------------------
// C[M,N] = act(A[M,K] @ W[K,N] + bias) (+ res).  Tile 128x128, BK=64.
// 4 waves, each owns a 64x64 quadrant = 4x4 fragments of 16x16.
// LDS tiles [row][64 bf16] with 16B-slot XOR swizzle (slot ^= row&7).
__global__ __launch_bounds__(256, 2) void gemm_mfma_kernel(
    const float* __restrict__ A, int lda,
    const unsigned int* __restrict__ Wp,     // packed hi|lo<<16, [K][N]
    const float* __restrict__ bias,
    const float* __restrict__ res, int ldres,
    float* __restrict__ C, int ldc,
    int N, int K, int act)
{
    __shared__ __bf16 Ah[128 * 64];
    __shared__ __bf16 Al[128 * 64];
    __shared__ __bf16 Bh[128 * 64];
    __shared__ __bf16 Bl[128 * 64];

    const int tid = threadIdx.x;
    const int m0 = blockIdx.y * 128;
    const int n0 = blockIdx.x * 128;
    const int lane = tid & 63;
    const int w = tid >> 6;
    const int wm = (w >> 1) * 64;
    const int wn = (w & 1) * 64;

    f32x4 acc[4][4];
    #pragma unroll
    for (int i = 0; i < 4; ++i)
        #pragma unroll
        for (int j = 0; j < 4; ++j) acc[i][j] = (f32x4){0.f, 0.f, 0.f, 0.f};

    const int ar = tid >> 1;           // A staging row 0..127
    const int ak = (tid & 1) * 32;     // A k-offset
    const int bc = tid & 127;          // B staging col 0..127
    const int bk = (tid >> 7) * 32;    // B k-offset 0/32
    const int bcol = n0 + bc;
    const bool bok = bcol < N;

    for (int k0 = 0; k0 < K; k0 += 64) {
        __syncthreads();
        // ---- stage A (fp32 -> bf16 hi/lo), row-contiguous loads ----
        {
            const float* src = A + (size_t)(m0 + ar) * lda + k0 + ak;
            float va[32];
            #pragma unroll
            for (int i = 0; i < 8; ++i) {
                float4 v = ((const float4*)src)[i];
                va[i * 4 + 0] = v.x; va[i * 4 + 1] = v.y;
                va[i * 4 + 2] = v.z; va[i * 4 + 3] = v.w;
            }
            #pragma unroll
            for (int s = 0; s < 4; ++s) {
                const int slot = (ak >> 3) + s;
                const int swz = slot ^ (ar & 7);
                bf16x8 hh, ll;
                #pragma unroll
                for (int j = 0; j < 8; ++j) {
                    const float xv = va[s * 8 + j];
                    const __bf16 h = (__bf16)xv;
                    hh[j] = h;
                    ll[j] = (__bf16)(xv - (float)h);
                }
                *(bf16x8*)&Ah[ar * 64 + swz * 8] = hh;
                *(bf16x8*)&Al[ar * 64 + swz * 8] = ll;
            }
        }
        // ---- stage B from packed weights (coalesced dword loads) ----
        {
            const unsigned int* src = Wp + (size_t)(k0 + bk) * N + bcol;
            unsigned int up[32];
            #pragma unroll
            for (int j = 0; j < 32; ++j)
                up[j] = bok ? src[(size_t)j * N] : 0u;
            #pragma unroll
            for (int s = 0; s < 4; ++s) {
                const int slot = (bk >> 3) + s;
                const int swz = slot ^ (bc & 7);
                bf16x8 hh, ll;
                #pragma unroll
                for (int j = 0; j < 8; ++j) {
                    const unsigned int p = up[s * 8 + j];
                    hh[j] = __builtin_bit_cast(__bf16, (unsigned short)(p & 0xffffu));
                    ll[j] = __builtin_bit_cast(__bf16, (unsigned short)(p >> 16));
                }
                *(bf16x8*)&Bh[bc * 64 + swz * 8] = hh;
                *(bf16x8*)&Bl[bc * 64 + swz * 8] = ll;
            }
        }
        __syncthreads();

        #pragma unroll
        for (int kc = 0; kc < 2; ++kc) {
            bf16x8 fAh[4], fAl[4], fBh[4], fBl[4];
            #pragma unroll
            for (int i = 0; i < 4; ++i) {
                const int row = wm + i * 16 + (lane & 15);
                const int slot = kc * 4 + (lane >> 4);
                const int offa = row * 64 + (slot ^ (row & 7)) * 8;
                fAh[i] = *(const bf16x8*)&Ah[offa];
                fAl[i] = *(const bf16x8*)&Al[offa];
                const int col = wn + i * 16 + (lane & 15);
                const int offb = col * 64 + (slot ^ (col & 7)) * 8;
                fBh[i] = *(const bf16x8*)&Bh[offb];
                fBl[i] = *(const bf16x8*)&Bl[offb];
            }
            #pragma unroll
            for (int i = 0; i < 4; ++i)
                #pragma unroll
                for (int j = 0; j < 4; ++j) {
                    acc[i][j] = __builtin_amdgcn_mfma_f32_16x16x32_bf16(
                        fAl[i], fBh[j], acc[i][j], 0, 0, 0);
                    acc[i][j] = __builtin_amdgcn_mfma_f32_16x16x32_bf16(
                        fAh[i], fBl[j], acc[i][j], 0, 0, 0);
                    acc[i][j] = __builtin_amdgcn_mfma_f32_16x16x32_bf16(
                        fAh[i], fBh[j], acc[i][j], 0, 0, 0);
                }
        }
    }

    // ---- epilogue: C/D layout col=lane&15, row=(lane>>4)*4+r ----
    const int rb = (lane >> 4) * 4;
    const int cc = lane & 15;
    #pragma unroll
    for (int j = 0; j < 4; ++j) {
        const int col = n0 + wn + j * 16 + cc;
        if (col >= N) continue;
        const float bv = bias[col];
        #pragma unroll
        for (int i = 0; i < 4; ++i) {
            #pragma unroll
            for (int r = 0; r < 4; ++r) {
                const int row = m0 + wm + i * 16 + rb + r;
                float v = acc[i][j][r] + bv;
                if (act == 1) {
                    const float t = 0.7978845608028654f * (v + 0.044715f * v * v * v);
                    v = 0.5f * v * (1.0f + tanhf(t));
                }
                if (res) v += res[(size_t)row * ldres + col];
                C[(size_t)row * ldc + col] = v;
            }
        }
    }
}

// ------------------------------- RoPE ---------------------------------------
__global__ void rope_kernel(float* __restrict__ buf, int dim, int npairs)
{
    const int idx = blockIdx.x * blockDim.x + threadIdx.x;
    if (idx >= npairs) return;
    const int hp = dim >> 1;
    const int row = idx / hp;
    const int p = idx - row * hp;
    const int t = row & 2047;   // T = 2048
    const float theta = expf((float)p * (-2.0f / (float)dim) * 9.210340371976184f);
    const float pf = (float)(t + 1) * theta;          // fp32 product, like ref
    double ang = fmod((double)pf, 6.283185307179586476925286766559);
    const float c = (float)cos(ang);
    const float s = (float)sin(ang);
    float* pr = buf + (size_t)row * dim + 2 * p;
    const float x0 = pr[0], x1 = pr[1];
    pr[0] = x0 * c - x1 * s;
    pr[1] = x1 * c + x0 * s;
}

// ---------------------- MFMA flash causal attention -------------------------
// dk=96 (64 nope + 32 rope), dv=64. QBLK=64 (4 waves x 16 q-rows), KVBLK=32.
// QK^T: (Qh+Ql)x(Kh+Kl) 3-term split.  PV: P(bf16) x (Vh+Vl).
// Grid (32, NH, B), qt reversed so longest blocks launch first. Block 256.
#define KS  104   // K row stride (96+8):   208B = 20 banks mod 32 -> 2-way, free
#define VTS 40    // Vt row stride (32+8):  80B, 16B-aligned, 20 banks -> free
#define PS  40    // P row stride
__global__ __launch_bounds__(256) void attn_mfma_kernel(
    const float* __restrict__ q,    // [4096][1024]  head h at col h*64
    const float* __restrict__ qr,   // [4096][512]   head h at col h*32
    const float* __restrict__ kv,   // [4096][2048]  k at h*64, v at 1024+h*64
    const float* __restrict__ kr,   // [4096][32]    shared across heads
    float* __restrict__ att)        // [4096][1024]  head h at col h*64
{
    __shared__ __bf16 Kh[32 * KS];
    __shared__ __bf16 Kl[32 * KS];
    __shared__ __bf16 Vth[64 * VTS];   // V transposed [d][kv]
    __shared__ __bf16 Vtl[64 * VTS];
    __shared__ __bf16 P[64 * PS];      // [q][kv], wave-local rows

    const int qt = (int)gridDim.x - 1 - (int)blockIdx.x;
    const int h = blockIdx.y, b = blockIdx.z;
    const int tid = threadIdx.x;
    const int lane = tid & 63;
    const int w = tid >> 6;
    const int lg = lane >> 4;          // lane group 0..3 (k-slot / row group)
    const int l15 = lane & 15;
    const int rowQ0 = b * 2048 + qt * 64;
    const int rowK0 = b * 2048;
    const float scale = 0.10206207261596575f;  // 1/sqrt(96)

    // ---- Q fragments direct from global (scaled, hi/lo split), hoisted ----
    bf16x8 fQh[3], fQl[3];
    {
        const int grow = rowQ0 + w * 16 + l15;
        #pragma unroll
        for (int kc = 0; kc < 3; ++kc) {
            const float* src = (kc < 2)
                ? q + (size_t)grow * 1024 + h * 64 + kc * 32 + lg * 8
                : qr + (size_t)grow * 512 + h * 32 + lg * 8;
            #pragma unroll
            for (int j = 0; j < 8; ++j) {
                const float v = src[j] * scale;
                const __bf16 hi = (__bf16)v;
                fQh[kc][j] = hi;
                fQl[kc][j] = (__bf16)(v - (float)hi);
            }
        }
    }

    f32x4 accO[4];
    #pragma unroll
    for (int jd = 0; jd < 4; ++jd) accO[jd] = (f32x4){0.f, 0.f, 0.f, 0.f};
    float mold[4] = {-1e30f, -1e30f, -1e30f, -1e30f};
    float lsum[4] = {0.f, 0.f, 0.f, 0.f};

    const int ntiles = 2 * qt + 2;
    for (int kt = 0; kt < ntiles; ++kt) {
        __syncthreads();   // prev iteration's K/V reads done before overwrite
        // ---- stage K hi/lo: 32 x 96 ----
        #pragma unroll
        for (int i = 0; i < 12; ++i) {
            const int idx = tid + i * 256;
            const int r = idx / 96, c = idx - r * 96;
            const int grow = rowK0 + kt * 32 + r;
            const float v = (c < 64) ? kv[(size_t)grow * 2048 + h * 64 + c]
                                     : kr[(size_t)grow * 32 + (c - 64)];
            const __bf16 hi = (__bf16)v;
            Kh[r * KS + c] = hi;
            Kl[r * KS + c] = (__bf16)(v - (float)hi);
        }
        // ---- stage V transposed hi/lo: [d][kv] ----
        #pragma unroll
        for (int i = 0; i < 8; ++i) {
            const int idx = tid + i * 256;
            const int r = idx >> 6, c = idx & 63;   // r=kv row, c=d
            const float v = kv[(size_t)(rowK0 + kt * 32 + r) * 2048 + 1024 + h * 64 + c];
            const __bf16 hi = (__bf16)v;
            Vth[c * VTS + r] = hi;
            Vtl[c * VTS + r] = (__bf16)(v - (float)hi);
        }
        __syncthreads();

        // ---- S = Q K^T (3-term split) ----
        f32x4 accS[2];
        accS[0] = (f32x4){0.f, 0.f, 0.f, 0.f};
        accS[1] = (f32x4){0.f, 0.f, 0.f, 0.f};
        #pragma unroll
        for (int jt = 0; jt < 2; ++jt) {
            #pragma unroll
            for (int kc = 0; kc < 3; ++kc) {
                const int off = (jt * 16 + l15) * KS + kc * 32 + lg * 8;
                const bf16x8 fKh = *(const bf16x8*)&Kh[off];
                const bf16x8 fKl = *(const bf16x8*)&Kl[off];
                accS[jt] = __builtin_amdgcn_mfma_f32_16x16x32_bf16(
                    fQl[kc], fKh, accS[jt], 0, 0, 0);
                accS[jt] = __builtin_amdgcn_mfma_f32_16x16x32_bf16(
                    fQh[kc], fKl, accS[jt], 0, 0, 0);
                accS[jt] = __builtin_amdgcn_mfma_f32_16x16x32_bf16(
                    fQh[kc], fKh, accS[jt], 0, 0, 0);
            }
        }

        // ---- causal mask (only diagonal tiles) ----
        if (kt >= 2 * qt) {
            const int qg = qt * 64 + w * 16 + lg * 4;
            #pragma unroll
            for (int jt = 0; jt < 2; ++jt) {
                const int kvg = kt * 32 + jt * 16 + l15;
                #pragma unroll
                for (int r = 0; r < 4; ++r)
                    if (kvg > qg + r) accS[jt][r] = -1e30f;
            }
        }

        // ---- online softmax (rows live in 16-lane groups) ----
        float rs[4];
        #pragma unroll
        for (int r = 0; r < 4; ++r) {
            float mr = fmaxf(accS[0][r], accS[1][r]);
            #pragma unroll
            for (int m = 1; m < 16; m <<= 1) mr = fmaxf(mr, __shfl_xor(mr, m, 64));
            const float mnew = fmaxf(mold[r], mr);
            rs[r] = expf(mold[r] - mnew);
            const float p0 = expf(accS[0][r] - mnew);
            const float p1 = expf(accS[1][r] - mnew);
            float sum = p0 + p1;
            #pragma unroll
            for (int m = 1; m < 16; m <<= 1) sum += __shfl_xor(sum, m, 64);
            lsum[r] = lsum[r] * rs[r] + sum;
            mold[r] = mnew;
            const int prow = (w * 16 + lg * 4 + r) * PS;
            P[prow + l15] = (__bf16)p0;
            P[prow + 16 + l15] = (__bf16)p1;
        }

        // ---- rescale O, then PV (P bf16 x V split) ----
        #pragma unroll
        for (int jd = 0; jd < 4; ++jd)
            #pragma unroll
            for (int r = 0; r < 4; ++r) accO[jd][r] *= rs[r];

        const bf16x8 fP = *(const bf16x8*)&P[(w * 16 + l15) * PS + lg * 8];
        #pragma unroll
        for (int jd = 0; jd < 4; ++jd) {
            const int off = (jd * 16 + l15) * VTS + lg * 8;
            const bf16x8 fVh = *(const bf16x8*)&Vth[off];
            const bf16x8 fVl = *(const bf16x8*)&Vtl[off];
            accO[jd] = __builtin_amdgcn_mfma_f32_16x16x32_bf16(fP, fVh, accO[jd], 0, 0, 0);
            accO[jd] = __builtin_amdgcn_mfma_f32_16x16x32_bf16(fP, fVl, accO[jd], 0, 0, 0);
        }
    }

    // ---- epilogue ----
    #pragma unroll
    for (int r = 0; r < 4; ++r) {
        const float linv = 1.0f / lsum[r];
        const int grow = rowQ0 + w * 16 + lg * 4 + r;
        #pragma unroll
        for (int jd = 0; jd < 4; ++jd)
            att[(size_t)grow * 1024 + h * 64 + jd * 16 + l15] = accO[jd][r] * linv;
    }
}

static inline void gemm(hipStream_t s, const float* A, int lda,
                        const unsigned int* Wp,
                        const float* bias, const float* res, int ldres,
                        float* C, int ldc, int M, int N, int K, int act)
{
    dim3 grid((N + 127) / 128, M / 128);
    gemm_mfma_kernel<<<grid, 256, 0, s>>>(A, lda, Wp, bias, res, ldres,
                                          C, ldc, N, K, act);
}

static inline void split_pack(hipStream_t s, const float* w, unsigned int* wp, int n)
{
    const int n4 = n >> 2;
    const int blocks = (n4 + 255) / 256 < 2048 ? (n4 + 255) / 256 : 2048;
    split_pack_kernel<<<blocks, 256, 0, s>>>(w, wp, n4);
}

extern "C" void kernel_launch(void* const* d_in, const int* in_sizes, int n_in,
                              void* d_out, int out_size, void* d_ws, size_t ws_size,
                              hipStream_t stream)
{
    const float* x   = (const float*)d_in[0];
    const float* w1  = (const float*)d_in[1];
    const float* b1  = (const float*)d_in[2];
    const float* wkr = (const float*)d_in[3];
    const float* bkr = (const float*)d_in[4];
    const float* wqr = (const float*)d_in[5];
    const float* bqr = (const float*)d_in[6];
    const float* wkv = (const float*)d_in[7];
    const float* bkv = (const float*)d_in[8];
    const float* wq  = (const float*)d_in[9];
    const float* bq  = (const float*)d_in[10];
    const float* wo  = (const float*)d_in[11];
    const float* bo  = (const float*)d_in[12];
    const float* wi  = (const float*)d_in[13];
    const float* bi  = (const float*)d_in[14];
    const float* wo2 = (const float*)d_in[15];
    const float* bo2 = (const float*)d_in[16];
    const float* g1  = (const float*)d_in[17];
    const float* g2  = (const float*)d_in[18];
    float* out = (float*)d_out;
    float* ws  = (float*)d_ws;

    const size_t MF = (size_t)1 << 20;
    float* xn  = ws;              // 4MF, reused as xn2
    float* hb  = ws + 4 * MF;     // 4MF
    float* kvb = ws + 8 * MF;     // 8MF
    float* qb  = ws + 16 * MF;    // 4MF
    float* qrb = ws + 20 * MF;    // 2MF
    float* krb = ws + 22 * MF;    // 128K floats
    float* attb = hb;
    float* ffh  = hb;             // 16MF spanning hb,kvb,qb (all dead by then)
    unsigned int* w1p  = (unsigned int*)(ws + 23 * MF);  // 1M
    unsigned int* wkrp = (unsigned int*)(ws + 24 * MF);  // 32K
    unsigned int* wqrp = (unsigned int*)(ws + 25 * MF);  // 512K
    unsigned int* wkvp = (unsigned int*)(ws + 26 * MF);  // 1M
    unsigned int* wqp  = (unsigned int*)(ws + 27 * MF);  // 512K
    unsigned int* wop  = (unsigned int*)(ws + 28 * MF);  // 1M
    unsigned int* wip  = (unsigned int*)(ws + 29 * MF);  // 4M
    unsigned int* wo2p = (unsigned int*)(ws + 33 * MF);  // 4M  -> total 37MF

    // ---- weight split precompute (every launch; ws is re-poisoned) ----
    split_pack(stream, w1,  w1p,  1024 * 1024);
    split_pack(stream, wkr, wkrp, 1024 * 32);
    split_pack(stream, wqr, wqrp, 1024 * 512);
    split_pack(stream, wkv, wkvp, 512 * 2048);
    split_pack(stream, wq,  wqp,  512 * 1024);
    split_pack(stream, wo,  wop,  1024 * 1024);
    split_pack(stream, wi,  wip,  1024 * 4096);
    split_pack(stream, wo2, wo2p, 4096 * 1024);

    // ---- attention branch ----
    rmsnorm_kernel<<<4096, 256, 0, stream>>>(x, g1, xn);
    gemm(stream, xn, 1024, w1p, b1, nullptr, 0, hb, 1024, 4096, 1024, 1024, 0);
    gemm(stream, hb, 1024, wkrp, bkr, nullptr, 0, krb, 32, 4096, 32, 1024, 0);
    gemm(stream, hb, 1024, wqrp, bqr, nullptr, 0, qrb, 512, 4096, 512, 1024, 0);
    gemm(stream, hb, 1024, wkvp, bkv, nullptr, 0, kvb, 2048, 4096, 2048, 512, 0);
    gemm(stream, hb + 512, 1024, wqp, bq, nullptr, 0, qb, 1024, 4096, 1024, 512, 0);
    rope_kernel<<<(4096 * 16 + 255) / 256, 256, 0, stream>>>(krb, 32, 4096 * 16);
    rope_kernel<<<(4096 * 256 + 255) / 256, 256, 0, stream>>>(qrb, 512, 4096 * 256);
    attn_mfma_kernel<<<dim3(32, 16, 2), 256, 0, stream>>>(qb, qrb, kvb, krb, attb);
    gemm(stream, attb, 1024, wop, bo, x, 1024, out, 1024, 4096, 1024, 1024, 0);

    // ---- FFN branch ----
    rmsnorm_kernel<<<4096, 256, 0, stream>>>(out, g2, xn);
    gemm(stream, xn, 1024, wip, bi, nullptr, 0, ffh, 4096, 4096, 4096, 1024, 1);
    gemm(stream, ffh, 4096, wo2p, bo2, out, 1024, out, 1024, 4096, 1024, 4096, 0);
}

// Round 7
// 969.738 us; speedup vs baseline: 2.0618x; 1.2760x over previous
//
#include <hip/hip_runtime.h>
#include <math.h>

// ---------------------------------------------------------------------------
// MLA transformer block. B=2, T=2048, C=1024, NH=16, HD=64, DHR=32, L=512.
// M = B*T = 4096 rows.
//
// All matmuls on bf16 MFMA with 2-term split (X ~= Xh + Xl, bf16 each).
// Activations are stored PACKED: u32 = bf16_hi | bf16_lo<<16, produced by the
// upstream kernel's epilogue, so the split is computed once per element.
// Attention: swapped QK^T (mfma(K,Q) -> S^T, q on C/D column => per-lane
// softmax with 2-shfl reduce), P single bf16, V single bf16 (hi only).
// Load balance: each block processes q-tiles {x, 31-x} => constant work.
//
// Workspace (4B elements, 1MF = 1<<20):
//   xnp   @ 0    (4MF)  : packed rmsnorm output (reused for xn2)
//   hbp   @ 4MF  (4MF)  : packed h   (later: attbp, ffhp start)
//   kvbp  @ 8MF  (8MF)  : packed kv            [4096 x 2048]
//   qbp   @ 16MF (4MF)  : packed q             [4096 x 1024]
//   qrbp  @ 20MF (2MF)  : packed qr (rope'd)   [4096 x 512]
//   krbp  @ 22MF (128K) : packed kr (rope'd)   [4096 x 32]
//   ffhp  = 4MF..20MF   : packed gelu(xn2@wi+bi) [4096 x 4096]
//   packed weights @ 23MF.. : w1p(1M) wkrp wqrp wkvp wqp wop wip(4M) wo2p(4M)
// Total = 37MF * 4B = 148 MB.
// ---------------------------------------------------------------------------

typedef __attribute__((ext_vector_type(8))) __bf16 bf16x8;
typedef __attribute__((ext_vector_type(4))) float f32x4;

__device__ __forceinline__ __bf16 bfbits(unsigned int u) {
    return __builtin_bit_cast(__bf16, (unsigned short)u);   // low 16 bits
}
__device__ __forceinline__ unsigned int packsplit(float x) {
    const __bf16 h = (__bf16)x;
    const __bf16 l = (__bf16)(x - (float)h);
    return (unsigned int)__builtin_bit_cast(unsigned short, h)
         | ((unsigned int)__builtin_bit_cast(unsigned short, l) << 16);
}
__device__ __forceinline__ float unpackf(unsigned int u) {
    const float hi = __builtin_bit_cast(float, u << 16);
    const float lo = __builtin_bit_cast(float, u & 0xffff0000u);
    return hi + lo;
}

// ------------------- weight hi/lo split precompute --------------------------
__global__ __launch_bounds__(256) void split_pack_kernel(
    const float* __restrict__ w, unsigned int* __restrict__ wp, int n4)
{
    int i = blockIdx.x * 256 + threadIdx.x;
    const int stride = gridDim.x * 256;
    for (; i < n4; i += stride) {
        const float4 v = ((const float4*)w)[i];
        uint4 o;
        o.x = packsplit(v.x); o.y = packsplit(v.y);
        o.z = packsplit(v.z); o.w = packsplit(v.w);
        ((uint4*)wp)[i] = o;
    }
}

// ---------------------------- RMSNorm (f32 in, packed out) ------------------
__global__ __launch_bounds__(256) void rmsnorm_kernel(
    const float* __restrict__ x, const float* __restrict__ g,
    unsigned int* __restrict__ outp)
{
    __shared__ float sm[4];
    const int row = blockIdx.x;
    const int tid = threadIdx.x;
    float4 v = ((const float4*)(x + (size_t)row * 1024))[tid];
    float ss = v.x * v.x + v.y * v.y + v.z * v.z + v.w * v.w;
    #pragma unroll
    for (int m = 32; m; m >>= 1) ss += __shfl_xor(ss, m, 64);
    if ((tid & 63) == 0) sm[tid >> 6] = ss;
    __syncthreads();
    const float total = sm[0] + sm[1] + sm[2] + sm[3];
    const float rstd = rsqrtf(total * (1.0f / 1024.0f) + 1e-6f);
    float4 gv = ((const float4*)g)[tid];
    uint4 o;
    o.x = packsplit(v.x * rstd * gv.x);
    o.y = packsplit(v.y * rstd * gv.y);
    o.z = packsplit(v.z * rstd * gv.z);
    o.w = packsplit(v.w * rstd * gv.w);
    ((uint4*)(outp + (size_t)row * 1024))[tid] = o;
}

// ------------------------ MFMA split-bf16 GEMM ------------------------------
// C = act(A @ W + bias) (+ res). A and W PACKED u32 (hi|lo<<16), [.][K]/[K][N].
// Outputs: Cf (f32, optional) and/or Cp (packed, optional).
// Tile 128x128, BK=64, 4 waves (2x2 of 64x64), 16B-slot XOR swizzle.
__global__ __launch_bounds__(256, 2) void gemm_mfma_kernel(
    const unsigned int* __restrict__ Ap, int lda,
    const unsigned int* __restrict__ Wp,
    const float* __restrict__ bias,
    const float* __restrict__ res, int ldres,
    float* __restrict__ Cf,
    unsigned int* __restrict__ Cp, int ldc,
    int N, int K, int act)
{
    __shared__ __bf16 Ah[128 * 64];
    __shared__ __bf16 Al[128 * 64];
    __shared__ __bf16 Bh[128 * 64];
    __shared__ __bf16 Bl[128 * 64];

    const int tid = threadIdx.x;
    const int m0 = blockIdx.y * 128;
    const int n0 = blockIdx.x * 128;
    const int lane = tid & 63;
    const int w = tid >> 6;
    const int wm = (w >> 1) * 64;
    const int wn = (w & 1) * 64;

    f32x4 acc[4][4];
    #pragma unroll
    for (int i = 0; i < 4; ++i)
        #pragma unroll
        for (int j = 0; j < 4; ++j) acc[i][j] = (f32x4){0.f, 0.f, 0.f, 0.f};

    const int ar = tid >> 1;           // A staging row 0..127
    const int ak = (tid & 1) * 32;     // A k-offset
    const int bc = tid & 127;          // B staging col 0..127
    const int bk = (tid >> 7) * 32;    // B k-offset 0/32
    const int bcol = n0 + bc;
    const bool bok = bcol < N;

    for (int k0 = 0; k0 < K; k0 += 64) {
        __syncthreads();
        // ---- stage A from packed (coalesced uint4 loads, 2 bit-ops/el) ----
        {
            const unsigned int* src = Ap + (size_t)(m0 + ar) * lda + k0 + ak;
            unsigned int ua[32];
            #pragma unroll
            for (int i = 0; i < 8; ++i) {
                uint4 v = ((const uint4*)src)[i];
                ua[i * 4 + 0] = v.x; ua[i * 4 + 1] = v.y;
                ua[i * 4 + 2] = v.z; ua[i * 4 + 3] = v.w;
            }
            #pragma unroll
            for (int s = 0; s < 4; ++s) {
                const int slot = (ak >> 3) + s;
                const int swz = slot ^ (ar & 7);
                bf16x8 hh, ll;
                #pragma unroll
                for (int j = 0; j < 8; ++j) {
                    const unsigned int p = ua[s * 8 + j];
                    hh[j] = bfbits(p);
                    ll[j] = bfbits(p >> 16);
                }
                *(bf16x8*)&Ah[ar * 64 + swz * 8] = hh;
                *(bf16x8*)&Al[ar * 64 + swz * 8] = ll;
            }
        }
        // ---- stage B from packed weights ----
        {
            const unsigned int* src = Wp + (size_t)(k0 + bk) * N + bcol;
            unsigned int up[32];
            #pragma unroll
            for (int j = 0; j < 32; ++j)
                up[j] = bok ? src[(size_t)j * N] : 0u;
            #pragma unroll
            for (int s = 0; s < 4; ++s) {
                const int slot = (bk >> 3) + s;
                const int swz = slot ^ (bc & 7);
                bf16x8 hh, ll;
                #pragma unroll
                for (int j = 0; j < 8; ++j) {
                    const unsigned int p = up[s * 8 + j];
                    hh[j] = bfbits(p);
                    ll[j] = bfbits(p >> 16);
                }
                *(bf16x8*)&Bh[bc * 64 + swz * 8] = hh;
                *(bf16x8*)&Bl[bc * 64 + swz * 8] = ll;
            }
        }
        __syncthreads();

        #pragma unroll
        for (int kc = 0; kc < 2; ++kc) {
            bf16x8 fAh[4], fAl[4], fBh[4], fBl[4];
            #pragma unroll
            for (int i = 0; i < 4; ++i) {
                const int row = wm + i * 16 + (lane & 15);
                const int slot = kc * 4 + (lane >> 4);
                const int offa = row * 64 + (slot ^ (row & 7)) * 8;
                fAh[i] = *(const bf16x8*)&Ah[offa];
                fAl[i] = *(const bf16x8*)&Al[offa];
                const int col = wn + i * 16 + (lane & 15);
                const int offb = col * 64 + (slot ^ (col & 7)) * 8;
                fBh[i] = *(const bf16x8*)&Bh[offb];
                fBl[i] = *(const bf16x8*)&Bl[offb];
            }
            #pragma unroll
            for (int i = 0; i < 4; ++i)
                #pragma unroll
                for (int j = 0; j < 4; ++j) {
                    acc[i][j] = __builtin_amdgcn_mfma_f32_16x16x32_bf16(
                        fAl[i], fBh[j], acc[i][j], 0, 0, 0);
                    acc[i][j] = __builtin_amdgcn_mfma_f32_16x16x32_bf16(
                        fAh[i], fBl[j], acc[i][j], 0, 0, 0);
                    acc[i][j] = __builtin_amdgcn_mfma_f32_16x16x32_bf16(
                        fAh[i], fBh[j], acc[i][j], 0, 0, 0);
                }
        }
    }

    // ---- epilogue: C/D layout col=lane&15, row=(lane>>4)*4+r ----
    const int rb = (lane >> 4) * 4;
    const int cc = lane & 15;
    #pragma unroll
    for (int j = 0; j < 4; ++j) {
        const int col = n0 + wn + j * 16 + cc;
        if (col >= N) continue;
        const float bv = bias[col];
        #pragma unroll
        for (int i = 0; i < 4; ++i) {
            #pragma unroll
            for (int r = 0; r < 4; ++r) {
                const int row = m0 + wm + i * 16 + rb + r;
                float v = acc[i][j][r] + bv;
                if (act == 1) {
                    const float t = 0.7978845608028654f * (v + 0.044715f * v * v * v);
                    v = 0.5f * v * (1.0f + tanhf(t));
                }
                if (res) v += res[(size_t)row * ldres + col];
                if (Cf) Cf[(size_t)row * ldc + col] = v;
                if (Cp) Cp[(size_t)row * ldc + col] = packsplit(v);
            }
        }
    }
}

// ------------------------------- RoPE (packed in/out) -----------------------
__global__ void rope_kernel(unsigned int* __restrict__ buf, int dim, int npairs)
{
    const int idx = blockIdx.x * blockDim.x + threadIdx.x;
    if (idx >= npairs) return;
    const int hp = dim >> 1;
    const int row = idx / hp;
    const int p = idx - row * hp;
    const int t = row & 2047;   // T = 2048
    const float theta = expf((float)p * (-2.0f / (float)dim) * 9.210340371976184f);
    const float pf = (float)(t + 1) * theta;          // fp32 product, like ref
    double ang = fmod((double)pf, 6.283185307179586476925286766559);
    const float c = (float)cos(ang);
    const float s = (float)sin(ang);
    unsigned int* pr = buf + (size_t)row * dim + 2 * p;
    const float x0 = unpackf(pr[0]), x1 = unpackf(pr[1]);
    pr[0] = packsplit(x0 * c - x1 * s);
    pr[1] = packsplit(x1 * c + x0 * s);
}

// ---------------------- MFMA flash causal attention -------------------------
// dk=96, dv=64. QBLK=64 (4 waves x 16 q-rows), KVBLK=32.
// Swapped QK^T: S^T = mfma(K, Q) => C/D col = q  => per-lane softmax state.
// PV: A = P (bf16, via wave-local LDS), B = V^T (hi only).
// Each block runs q-tiles {bx, 31-bx}: constant work => load-balanced.
#define KS  104   // K row stride: 208B, b128 frag reads bank-even
#define VTS 40    // Vt row stride: 80B, b128 reads bank-even
#define PSTR 40   // P row stride
__global__ __launch_bounds__(256) void attn_mfma_kernel(
    const unsigned int* __restrict__ q,    // packed [4096][1024]
    const unsigned int* __restrict__ qr,   // packed [4096][512]
    const unsigned int* __restrict__ kv,   // packed [4096][2048]
    const unsigned int* __restrict__ kr,   // packed [4096][32]
    unsigned int* __restrict__ att)        // packed [4096][1024]
{
    __shared__ __bf16 Kh[32 * KS];
    __shared__ __bf16 Kl[32 * KS];
    __shared__ __bf16 Vth[64 * VTS];   // V^T [d][kv], hi only
    __shared__ __bf16 P[64 * PSTR];    // P [q][kv], wave-local rows
    __shared__ float rsA[64], lsA[64];

    const int h = blockIdx.y, b = blockIdx.z;
    const int tid = threadIdx.x;
    const int lane = tid & 63;
    const int w = tid >> 6;
    const int lg = lane >> 4;
    const int l15 = lane & 15;
    const int rowK0 = b * 2048;
    const float scale = 0.10206207261596575f;  // 1/sqrt(96)

    #pragma unroll
    for (int ph = 0; ph < 2; ++ph) {
        const int qt = ph ? (31 - (int)blockIdx.x) : (int)blockIdx.x;
        const int rowQ0 = b * 2048 + qt * 64;
        const int qg = qt * 64 + w * 16 + l15;   // this lane's q row

        // ---- Q fragments from packed global (raw; scale applied to logits)
        bf16x8 fQh[3], fQl[3];
        {
            const int grow = rowQ0 + w * 16 + l15;
            #pragma unroll
            for (int kc = 0; kc < 3; ++kc) {
                const unsigned int* src = (kc < 2)
                    ? q + (size_t)grow * 1024 + h * 64 + kc * 32 + lg * 8
                    : qr + (size_t)grow * 512 + h * 32 + lg * 8;
                #pragma unroll
                for (int j = 0; j < 8; ++j) {
                    const unsigned int u = src[j];
                    fQh[kc][j] = bfbits(u);
                    fQl[kc][j] = bfbits(u >> 16);
                }
            }
        }

        f32x4 accO[4];
        #pragma unroll
        for (int jd = 0; jd < 4; ++jd) accO[jd] = (f32x4){0.f, 0.f, 0.f, 0.f};
        float mold = -1e30f, lsum = 0.f;

        const int ntiles = 2 * qt + 2;
        for (int kt = 0; kt < ntiles; ++kt) {
            __syncthreads();   // prev tile's K/V reads done before overwrite
            // ---- stage K cols 0..63 from kv (packed) ----
            #pragma unroll
            for (int i = 0; i < 8; ++i) {
                const int idx = tid + i * 256;
                const int r = idx >> 6, c = idx & 63;
                const unsigned int u =
                    kv[(size_t)(rowK0 + kt * 32 + r) * 2048 + h * 64 + c];
                Kh[r * KS + c] = bfbits(u);
                Kl[r * KS + c] = bfbits(u >> 16);
            }
            // ---- stage K cols 64..95 from kr ----
            #pragma unroll
            for (int i = 0; i < 4; ++i) {
                const int idx = tid + i * 256;
                const int r = idx >> 5, c = idx & 31;
                const unsigned int u =
                    kr[(size_t)(rowK0 + kt * 32 + r) * 32 + c];
                Kh[r * KS + 64 + c] = bfbits(u);
                Kl[r * KS + 64 + c] = bfbits(u >> 16);
            }
            // ---- stage V^T (hi only) ----
            #pragma unroll
            for (int i = 0; i < 8; ++i) {
                const int idx = tid + i * 256;
                const int r = idx >> 6, c = idx & 63;
                const unsigned int u =
                    kv[(size_t)(rowK0 + kt * 32 + r) * 2048 + 1024 + h * 64 + c];
                Vth[c * VTS + r] = bfbits(u);
            }
            __syncthreads();

            // ---- S^T = K Q^T (3-term split); C/D: col=q(l15), row=kv ----
            f32x4 accS[2];
            accS[0] = (f32x4){0.f, 0.f, 0.f, 0.f};
            accS[1] = (f32x4){0.f, 0.f, 0.f, 0.f};
            #pragma unroll
            for (int jt = 0; jt < 2; ++jt) {
                #pragma unroll
                for (int kc = 0; kc < 3; ++kc) {
                    const int off = (jt * 16 + l15) * KS + kc * 32 + lg * 8;
                    const bf16x8 fKh = *(const bf16x8*)&Kh[off];
                    const bf16x8 fKl = *(const bf16x8*)&Kl[off];
                    accS[jt] = __builtin_amdgcn_mfma_f32_16x16x32_bf16(
                        fKl, fQh[kc], accS[jt], 0, 0, 0);
                    accS[jt] = __builtin_amdgcn_mfma_f32_16x16x32_bf16(
                        fKh, fQl[kc], accS[jt], 0, 0, 0);
                    accS[jt] = __builtin_amdgcn_mfma_f32_16x16x32_bf16(
                        fKh, fQh[kc], accS[jt], 0, 0, 0);
                }
            }

            // ---- scale + causal mask (lane owns q=qg; rows are kv) ----
            float sv[2][4];
            #pragma unroll
            for (int jt = 0; jt < 2; ++jt)
                #pragma unroll
                for (int r = 0; r < 4; ++r) sv[jt][r] = accS[jt][r] * scale;
            if (kt * 32 + 31 > qt * 64 + w * 16) {
                #pragma unroll
                for (int jt = 0; jt < 2; ++jt)
                    #pragma unroll
                    for (int r = 0; r < 4; ++r) {
                        const int kvg = kt * 32 + jt * 16 + lg * 4 + r;
                        if (kvg > qg) sv[jt][r] = -1e30f;
                    }
            }

            // ---- per-lane online softmax (2-shfl reduce over 4 dup lanes) --
            float m8 = sv[0][0];
            #pragma unroll
            for (int jt = 0; jt < 2; ++jt)
                #pragma unroll
                for (int r = 0; r < 4; ++r) m8 = fmaxf(m8, sv[jt][r]);
            m8 = fmaxf(m8, __shfl_xor(m8, 16, 64));
            m8 = fmaxf(m8, __shfl_xor(m8, 32, 64));
            const float mnew = fmaxf(mold, m8);
            const float rs = expf(mold - mnew);
            float psum = 0.f;
            float pv[2][4];
            #pragma unroll
            for (int jt = 0; jt < 2; ++jt)
                #pragma unroll
                for (int r = 0; r < 4; ++r) {
                    const float p = expf(sv[jt][r] - mnew);
                    pv[jt][r] = p;
                    psum += p;
                }
            psum += __shfl_xor(psum, 16, 64);
            psum += __shfl_xor(psum, 32, 64);
            lsum = lsum * rs + psum;
            mold = mnew;

            // ---- P -> LDS as P[q][kv] (wave-local) ----
            #pragma unroll
            for (int jt = 0; jt < 2; ++jt)
                #pragma unroll
                for (int r = 0; r < 4; ++r)
                    P[(w * 16 + l15) * PSTR + jt * 16 + lg * 4 + r] =
                        (__bf16)pv[jt][r];
            if (lane < 16) rsA[w * 16 + lane] = rs;
            const f32x4 rsv = *(const f32x4*)&rsA[w * 16 + lg * 4];

            // ---- rescale O, then PV: accO(col=d,row=q) += P x V^T ----
            #pragma unroll
            for (int jd = 0; jd < 4; ++jd)
                #pragma unroll
                for (int r = 0; r < 4; ++r) accO[jd][r] *= rsv[r];

            const bf16x8 fP = *(const bf16x8*)&P[(w * 16 + l15) * PSTR + lg * 8];
            #pragma unroll
            for (int jd = 0; jd < 4; ++jd) {
                const bf16x8 fV = *(const bf16x8*)&Vth[(jd * 16 + l15) * VTS + lg * 8];
                accO[jd] = __builtin_amdgcn_mfma_f32_16x16x32_bf16(
                    fP, fV, accO[jd], 0, 0, 0);
            }
        }

        // ---- epilogue: packed writes ----
        if (lane < 16) lsA[w * 16 + lane] = lsum;
        const f32x4 lsv = *(const f32x4*)&lsA[w * 16 + lg * 4];
        #pragma unroll
        for (int r = 0; r < 4; ++r) {
            const float linv = 1.0f / lsv[r];
            const int grow = rowQ0 + w * 16 + lg * 4 + r;
            #pragma unroll
            for (int jd = 0; jd < 4; ++jd)
                att[(size_t)grow * 1024 + h * 64 + jd * 16 + l15] =
                    packsplit(accO[jd][r] * linv);
        }
    }
}

static inline void gemm(hipStream_t s, const unsigned int* Ap, int lda,
                        const unsigned int* Wp,
                        const float* bias, const float* res, int ldres,
                        float* Cf, unsigned int* Cp, int ldc,
                        int M, int N, int K, int act)
{
    dim3 grid((N + 127) / 128, M / 128);
    gemm_mfma_kernel<<<grid, 256, 0, s>>>(Ap, lda, Wp, bias, res, ldres,
                                          Cf, Cp, ldc, N, K, act);
}

static inline void split_pack(hipStream_t s, const float* w, unsigned int* wp, int n)
{
    const int n4 = n >> 2;
    const int blocks = (n4 + 255) / 256 < 2048 ? (n4 + 255) / 256 : 2048;
    split_pack_kernel<<<blocks, 256, 0, s>>>(w, wp, n4);
}

extern "C" void kernel_launch(void* const* d_in, const int* in_sizes, int n_in,
                              void* d_out, int out_size, void* d_ws, size_t ws_size,
                              hipStream_t stream)
{
    const float* x   = (const float*)d_in[0];
    const float* w1  = (const float*)d_in[1];
    const float* b1  = (const float*)d_in[2];
    const float* wkr = (const float*)d_in[3];
    const float* bkr = (const float*)d_in[4];
    const float* wqr = (const float*)d_in[5];
    const float* bqr = (const float*)d_in[6];
    const float* wkv = (const float*)d_in[7];
    const float* bkv = (const float*)d_in[8];
    const float* wq  = (const float*)d_in[9];
    const float* bq  = (const float*)d_in[10];
    const float* wo  = (const float*)d_in[11];
    const float* bo  = (const float*)d_in[12];
    const float* wi  = (const float*)d_in[13];
    const float* bi  = (const float*)d_in[14];
    const float* wo2 = (const float*)d_in[15];
    const float* bo2 = (const float*)d_in[16];
    const float* g1  = (const float*)d_in[17];
    const float* g2  = (const float*)d_in[18];
    float* out = (float*)d_out;
    float* ws  = (float*)d_ws;

    const size_t MF = (size_t)1 << 20;
    unsigned int* xnp  = (unsigned int*)ws;              // 4MF
    unsigned int* hbp  = (unsigned int*)(ws + 4 * MF);   // 4MF
    unsigned int* kvbp = (unsigned int*)(ws + 8 * MF);   // 8MF
    unsigned int* qbp  = (unsigned int*)(ws + 16 * MF);  // 4MF
    unsigned int* qrbp = (unsigned int*)(ws + 20 * MF);  // 2MF
    unsigned int* krbp = (unsigned int*)(ws + 22 * MF);  // 128K
    unsigned int* attbp = hbp;           // hb dead after q-GEMM
    unsigned int* ffhp  = hbp;           // spans 4MF..20MF, all dead by FFN
    unsigned int* w1p  = (unsigned int*)(ws + 23 * MF);  // 1M
    unsigned int* wkrp = (unsigned int*)(ws + 24 * MF);  // 32K
    unsigned int* wqrp = (unsigned int*)(ws + 25 * MF);  // 512K
    unsigned int* wkvp = (unsigned int*)(ws + 26 * MF);  // 1M
    unsigned int* wqp  = (unsigned int*)(ws + 27 * MF);  // 512K
    unsigned int* wop  = (unsigned int*)(ws + 28 * MF);  // 1M
    unsigned int* wip  = (unsigned int*)(ws + 29 * MF);  // 4M
    unsigned int* wo2p = (unsigned int*)(ws + 33 * MF);  // 4M -> total 37MF

    // ---- weight split precompute ----
    split_pack(stream, w1,  w1p,  1024 * 1024);
    split_pack(stream, wkr, wkrp, 1024 * 32);
    split_pack(stream, wqr, wqrp, 1024 * 512);
    split_pack(stream, wkv, wkvp, 512 * 2048);
    split_pack(stream, wq,  wqp,  512 * 1024);
    split_pack(stream, wo,  wop,  1024 * 1024);
    split_pack(stream, wi,  wip,  1024 * 4096);
    split_pack(stream, wo2, wo2p, 4096 * 1024);

    // ---- attention branch ----
    rmsnorm_kernel<<<4096, 256, 0, stream>>>(x, g1, xnp);
    gemm(stream, xnp, 1024, w1p, b1, nullptr, 0, nullptr, hbp, 1024,
         4096, 1024, 1024, 0);
    gemm(stream, hbp, 1024, wkrp, bkr, nullptr, 0, nullptr, krbp, 32,
         4096, 32, 1024, 0);
    gemm(stream, hbp, 1024, wqrp, bqr, nullptr, 0, nullptr, qrbp, 512,
         4096, 512, 1024, 0);
    gemm(stream, hbp, 1024, wkvp, bkv, nullptr, 0, nullptr, kvbp, 2048,
         4096, 2048, 512, 0);
    gemm(stream, hbp + 512, 1024, wqp, bq, nullptr, 0, nullptr, qbp, 1024,
         4096, 1024, 512, 0);
    rope_kernel<<<(4096 * 16 + 255) / 256, 256, 0, stream>>>(krbp, 32, 4096 * 16);
    rope_kernel<<<(4096 * 256 + 255) / 256, 256, 0, stream>>>(qrbp, 512, 4096 * 256);
    attn_mfma_kernel<<<dim3(16, 16, 2), 256, 0, stream>>>(qbp, qrbp, kvbp, krbp, attbp);
    gemm(stream, attbp, 1024, wop, bo, x, 1024, out, nullptr, 1024,
         4096, 1024, 1024, 0);

    // ---- FFN branch ----
    rmsnorm_kernel<<<4096, 256, 0, stream>>>(out, g2, xnp);
    gemm(stream, xnp, 1024, wip, bi, nullptr, 0, nullptr, ffhp, 4096,
         4096, 4096, 1024, 1);
    gemm(stream, ffhp, 4096, wo2p, bo2, out, 1024, out, nullptr, 1024,
         4096, 1024, 4096, 0);
}

// Round 10
// 867.695 us; speedup vs baseline: 2.3042x; 1.1176x over previous
//
#include <hip/hip_runtime.h>
#include <math.h>

// ---------------------------------------------------------------------------
// MLA transformer block. B=2, T=2048, C=1024, NH=16, HD=64, DHR=32, L=512.
// M = B*T = 4096 rows.
//
// All matmuls on bf16 MFMA with 2-term split (X ~= Xh + Xl, bf16 each),
// 3-term product AhBh + AhBl + AlBh. Activations AND weights stored PACKED:
// u32 = bf16_hi | bf16_lo<<16. Weights additionally pre-TRANSPOSED to
// [N][K] so both GEMM operands stage with row-contiguous async
// global_load_lds into linear LDS (XOR slot swizzle, source pre-swizzled),
// double-buffered BK=32 with next-tile loads issued before compute.
//
// Attention: swapped QK^T (mfma(K,Q) -> S^T, per-lane softmax), P bf16,
// V hi-only. Blocks pair q-tiles {x, 31-x} for load balance.
//
// Workspace (4B elements, 1MF = 1<<20):
//   xnp   @ 0    (4MF)  : packed rmsnorm output (reused for xn2)
//   hbp   @ 4MF  (4MF)  : packed h   (later: attbp, ffhp start)
//   kvbp  @ 8MF  (8MF)  : packed kv            [4096 x 2048]
//   qbp   @ 16MF (4MF)  : packed q             [4096 x 1024]
//   qrbp  @ 20MF (2MF)  : packed qr (rope'd)   [4096 x 512]
//   krbp  @ 22MF (128K) : packed kr (rope'd)   [4096 x 32]
//   ffhp  = 4MF..20MF   : packed gelu(xn2@wi+bi) [4096 x 4096]
//   packed transposed weights @ 23MF..37MF (row-padded to 128 where needed)
// Total = 37MF * 4B = 148 MB.
// ---------------------------------------------------------------------------

typedef __attribute__((ext_vector_type(8))) __bf16 bf16x8;
typedef __attribute__((ext_vector_type(4))) float f32x4;

__device__ __forceinline__ __bf16 bfbits(unsigned int u) {
    return __builtin_bit_cast(__bf16, (unsigned short)u);   // low 16 bits
}
__device__ __forceinline__ unsigned int packsplit(float x) {
    const __bf16 h = (__bf16)x;
    const __bf16 l = (__bf16)(x - (float)h);
    return (unsigned int)__builtin_bit_cast(unsigned short, h)
         | ((unsigned int)__builtin_bit_cast(unsigned short, l) << 16);
}
__device__ __forceinline__ float unpackf(unsigned int u) {
    const float hi = __builtin_bit_cast(float, u << 16);
    const float lo = __builtin_bit_cast(float, u & 0xffff0000u);
    return hi + lo;
}

// async 16B global -> LDS (wave-uniform LDS base + lane*16)
__device__ __forceinline__ void gl_lds16(const unsigned int* g, unsigned int* l) {
    __builtin_amdgcn_global_load_lds(
        (const __attribute__((address_space(1))) unsigned int*)g,
        (__attribute__((address_space(3))) unsigned int*)l,
        16, 0, 0);
}

// ---------------- weight transpose + hi/lo split pack -----------------------
// w[K][N] fp32 -> wt[N][K] packed u32. Grid (K/32, N/32), block 256.
__global__ __launch_bounds__(256) void transpose_pack_kernel(
    const float* __restrict__ w, unsigned int* __restrict__ wt,
    int N, int K)
{
    __shared__ float t[32][33];
    const int k0 = blockIdx.x * 32, n0 = blockIdx.y * 32;
    const int tx = threadIdx.x & 31, ty = threadIdx.x >> 5;   // 8 rows/pass
    #pragma unroll
    for (int r = 0; r < 4; ++r)
        t[ty + r * 8][tx] = w[(size_t)(k0 + ty + r * 8) * N + n0 + tx];
    __syncthreads();
    #pragma unroll
    for (int r = 0; r < 4; ++r)
        wt[(size_t)(n0 + ty + r * 8) * K + k0 + tx] =
            packsplit(t[tx][ty + r * 8]);
}

// ---------------------------- RMSNorm (f32 in, packed out) ------------------
__global__ __launch_bounds__(256) void rmsnorm_kernel(
    const float* __restrict__ x, const float* __restrict__ g,
    unsigned int* __restrict__ outp)
{
    __shared__ float sm[4];
    const int row = blockIdx.x;
    const int tid = threadIdx.x;
    float4 v = ((const float4*)(x + (size_t)row * 1024))[tid];
    float ss = v.x * v.x + v.y * v.y + v.z * v.z + v.w * v.w;
    #pragma unroll
    for (int m = 32; m; m >>= 1) ss += __shfl_xor(ss, m, 64);
    if ((tid & 63) == 0) sm[tid >> 6] = ss;
    __syncthreads();
    const float total = sm[0] + sm[1] + sm[2] + sm[3];
    const float rstd = rsqrtf(total * (1.0f / 1024.0f) + 1e-6f);
    float4 gv = ((const float4*)g)[tid];
    uint4 o;
    o.x = packsplit(v.x * rstd * gv.x);
    o.y = packsplit(v.y * rstd * gv.y);
    o.z = packsplit(v.z * rstd * gv.z);
    o.w = packsplit(v.w * rstd * gv.w);
    ((uint4*)(outp + (size_t)row * 1024))[tid] = o;
}

// ------------------------ MFMA split-bf16 GEMM ------------------------------
// C = act(A @ W + bias) (+ res). A packed [M][K] (lda), W packed TRANSPOSED
// [Npad][K] (ldb=K). Tile 128x128, BK=32, double-buffered async staging.
// LDS: per buffer A[128 rows][32 u32] linear + B same; slot' = slot^(row&7)
// swizzle applied on the GLOBAL source address and on the ds_read address.
__global__ __launch_bounds__(256, 2) void gemm_mfma_kernel(
    const unsigned int* __restrict__ Ap, int lda,
    const unsigned int* __restrict__ Bt, int ldb,
    const float* __restrict__ bias,
    const float* __restrict__ res, int ldres,
    float* __restrict__ Cf,
    unsigned int* __restrict__ Cp, int ldc,
    int N, int K, int act)
{
    __shared__ unsigned int lds[2][8192];   // [buf][A:0..4095 | B:4096..8191]

    const int tid = threadIdx.x;
    const int m0 = blockIdx.y * 128;
    const int n0 = blockIdx.x * 128;
    const int lane = tid & 63;
    const int w = tid >> 6;
    const int wm = (w >> 1) * 64;
    const int wn = (w & 1) * 64;
    const int l15 = lane & 15;
    const int lg = lane >> 4;

    // staging geometry: wave w, inst i covers tile rows w*32+i*8+(lane>>3),
    // 16B slot lane&7; source slot pre-swizzled so LDS (linear) ends up
    // holding slot' = slot ^ (row&7).
    const int srow = lane >> 3;
    const int sslot = lane & 7;
    const unsigned int* asrc[4];
    const unsigned int* bsrc[4];
    #pragma unroll
    for (int i = 0; i < 4; ++i) {
        const int row = w * 32 + i * 8 + srow;
        asrc[i] = Ap + (size_t)(m0 + row) * lda + (sslot ^ (row & 7)) * 4;
        bsrc[i] = Bt + (size_t)(n0 + row) * ldb + (sslot ^ (row & 7)) * 4;
    }

    f32x4 acc[4][4];
    #pragma unroll
    for (int i = 0; i < 4; ++i)
        #pragma unroll
        for (int j = 0; j < 4; ++j) acc[i][j] = (f32x4){0.f, 0.f, 0.f, 0.f};

    const int nt = K >> 5;

    // prologue: stage tile 0
    #pragma unroll
    for (int i = 0; i < 4; ++i) {
        gl_lds16(asrc[i], &lds[0][w * 1024 + i * 256]);
        gl_lds16(bsrc[i], &lds[0][4096 + w * 1024 + i * 256]);
    }
    __syncthreads();

    for (int t = 0; t < nt; ++t) {
        const int cur = t & 1;
        // ---- issue next tile's async loads (fly during compute) ----
        if (t + 1 < nt) {
            const int k1 = (t + 1) << 5;
            #pragma unroll
            for (int i = 0; i < 4; ++i) {
                gl_lds16(asrc[i] + k1, &lds[cur ^ 1][w * 1024 + i * 256]);
                gl_lds16(bsrc[i] + k1, &lds[cur ^ 1][4096 + w * 1024 + i * 256]);
            }
        }

        // ---- fragments: 2x ds_read_b128 + v_perm unpack per fragment ----
        bf16x8 fAh[4], fAl[4], fBh[4], fBl[4];
        #pragma unroll
        for (int i = 0; i < 4; ++i) {
            {
                const int row = wm + i * 16 + l15;
                const int s0 = (lg * 2) ^ (row & 7);
                const int s1 = (lg * 2 + 1) ^ (row & 7);
                const uint4 p0 = *(const uint4*)&lds[cur][row * 32 + s0 * 4];
                const uint4 p1 = *(const uint4*)&lds[cur][row * 32 + s1 * 4];
                uint4 h, l;
                h.x = __builtin_amdgcn_perm(p0.y, p0.x, 0x05040100u);
                l.x = __builtin_amdgcn_perm(p0.y, p0.x, 0x07060302u);
                h.y = __builtin_amdgcn_perm(p0.w, p0.z, 0x05040100u);
                l.y = __builtin_amdgcn_perm(p0.w, p0.z, 0x07060302u);
                h.z = __builtin_amdgcn_perm(p1.y, p1.x, 0x05040100u);
                l.z = __builtin_amdgcn_perm(p1.y, p1.x, 0x07060302u);
                h.w = __builtin_amdgcn_perm(p1.w, p1.z, 0x05040100u);
                l.w = __builtin_amdgcn_perm(p1.w, p1.z, 0x07060302u);
                fAh[i] = __builtin_bit_cast(bf16x8, h);
                fAl[i] = __builtin_bit_cast(bf16x8, l);
            }
            {
                const int row = wn + i * 16 + l15;
                const int s0 = (lg * 2) ^ (row & 7);
                const int s1 = (lg * 2 + 1) ^ (row & 7);
                const uint4 p0 = *(const uint4*)&lds[cur][4096 + row * 32 + s0 * 4];
                const uint4 p1 = *(const uint4*)&lds[cur][4096 + row * 32 + s1 * 4];
                uint4 h, l;
                h.x = __builtin_amdgcn_perm(p0.y, p0.x, 0x05040100u);
                l.x = __builtin_amdgcn_perm(p0.y, p0.x, 0x07060302u);
                h.y = __builtin_amdgcn_perm(p0.w, p0.z, 0x05040100u);
                l.y = __builtin_amdgcn_perm(p0.w, p0.z, 0x07060302u);
                h.z = __builtin_amdgcn_perm(p1.y, p1.x, 0x05040100u);
                l.z = __builtin_amdgcn_perm(p1.y, p1.x, 0x07060302u);
                h.w = __builtin_amdgcn_perm(p1.w, p1.z, 0x05040100u);
                l.w = __builtin_amdgcn_perm(p1.w, p1.z, 0x07060302u);
                fBh[i] = __builtin_bit_cast(bf16x8, h);
                fBl[i] = __builtin_bit_cast(bf16x8, l);
            }
        }

        #pragma unroll
        for (int i = 0; i < 4; ++i)
            #pragma unroll
            for (int j = 0; j < 4; ++j) {
                acc[i][j] = __builtin_amdgcn_mfma_f32_16x16x32_bf16(
                    fAl[i], fBh[j], acc[i][j], 0, 0, 0);
                acc[i][j] = __builtin_amdgcn_mfma_f32_16x16x32_bf16(
                    fAh[i], fBl[j], acc[i][j], 0, 0, 0);
                acc[i][j] = __builtin_amdgcn_mfma_f32_16x16x32_bf16(
                    fAh[i], fBh[j], acc[i][j], 0, 0, 0);
            }

        // drain next-tile loads (flew during compute) + join waves
        __syncthreads();
    }

    // ---- epilogue: C/D layout col=lane&15, row=(lane>>4)*4+r ----
    const int rb = (lane >> 4) * 4;
    const int cc = lane & 15;
    #pragma unroll
    for (int j = 0; j < 4; ++j) {
        const int col = n0 + wn + j * 16 + cc;
        if (col >= N) continue;
        const float bv = bias[col];
        #pragma unroll
        for (int i = 0; i < 4; ++i) {
            #pragma unroll
            for (int r = 0; r < 4; ++r) {
                const int row = m0 + wm + i * 16 + rb + r;
                float v = acc[i][j][r] + bv;
                if (act == 1) {
                    const float t = 0.7978845608028654f * (v + 0.044715f * v * v * v);
                    v = 0.5f * v * (1.0f + tanhf(t));
                }
                if (res) v += res[(size_t)row * ldres + col];
                if (Cf) Cf[(size_t)row * ldc + col] = v;
                if (Cp) Cp[(size_t)row * ldc + col] = packsplit(v);
            }
        }
    }
}

// ------------------------------- RoPE (packed in/out) -----------------------
__global__ void rope_kernel(unsigned int* __restrict__ buf, int dim, int npairs)
{
    const int idx = blockIdx.x * blockDim.x + threadIdx.x;
    if (idx >= npairs) return;
    const int hp = dim >> 1;
    const int row = idx / hp;
    const int p = idx - row * hp;
    const int t = row & 2047;   // T = 2048
    const float theta = expf((float)p * (-2.0f / (float)dim) * 9.210340371976184f);
    const float pf = (float)(t + 1) * theta;          // fp32 product, like ref
    double ang = fmod((double)pf, 6.283185307179586476925286766559);
    const float c = (float)cos(ang);
    const float s = (float)sin(ang);
    unsigned int* pr = buf + (size_t)row * dim + 2 * p;
    const float x0 = unpackf(pr[0]), x1 = unpackf(pr[1]);
    pr[0] = packsplit(x0 * c - x1 * s);
    pr[1] = packsplit(x1 * c + x0 * s);
}

// ---------------------- MFMA flash causal attention -------------------------
// dk=96, dv=64. QBLK=64 (4 waves x 16 q-rows), KVBLK=32.
// Swapped QK^T: S^T = mfma(K, Q) => C/D col = q  => per-lane softmax state.
// PV: A = P (bf16, via wave-local LDS), B = V^T (hi only).
// Each block runs q-tiles {bx, 31-bx}: constant work => load-balanced.
#define KS  104   // K row stride: 208B, b128 frag reads bank-even
#define VTS 40    // Vt row stride: 80B, b128 reads bank-even
#define PSTR 40   // P row stride
__global__ __launch_bounds__(256) void attn_mfma_kernel(
    const unsigned int* __restrict__ q,    // packed [4096][1024]
    const unsigned int* __restrict__ qr,   // packed [4096][512]
    const unsigned int* __restrict__ kv,   // packed [4096][2048]
    const unsigned int* __restrict__ kr,   // packed [4096][32]
    unsigned int* __restrict__ att)        // packed [4096][1024]
{
    __shared__ __bf16 Kh[32 * KS];
    __shared__ __bf16 Kl[32 * KS];
    __shared__ __bf16 Vth[64 * VTS];   // V^T [d][kv], hi only
    __shared__ __bf16 P[64 * PSTR];    // P [q][kv], wave-local rows
    __shared__ float rsA[64], lsA[64];

    const int h = blockIdx.y, b = blockIdx.z;
    const int tid = threadIdx.x;
    const int lane = tid & 63;
    const int w = tid >> 6;
    const int lg = lane >> 4;
    const int l15 = lane & 15;
    const int rowK0 = b * 2048;
    const float scale = 0.10206207261596575f;  // 1/sqrt(96)

    #pragma unroll
    for (int ph = 0; ph < 2; ++ph) {
        const int qt = ph ? (31 - (int)blockIdx.x) : (int)blockIdx.x;
        const int rowQ0 = b * 2048 + qt * 64;
        const int qg = qt * 64 + w * 16 + l15;   // this lane's q row

        // ---- Q fragments from packed global ----
        bf16x8 fQh[3], fQl[3];
        {
            const int grow = rowQ0 + w * 16 + l15;
            #pragma unroll
            for (int kc = 0; kc < 3; ++kc) {
                const unsigned int* src = (kc < 2)
                    ? q + (size_t)grow * 1024 + h * 64 + kc * 32 + lg * 8
                    : qr + (size_t)grow * 512 + h * 32 + lg * 8;
                #pragma unroll
                for (int j = 0; j < 8; ++j) {
                    const unsigned int u = src[j];
                    fQh[kc][j] = bfbits(u);
                    fQl[kc][j] = bfbits(u >> 16);
                }
            }
        }

        f32x4 accO[4];
        #pragma unroll
        for (int jd = 0; jd < 4; ++jd) accO[jd] = (f32x4){0.f, 0.f, 0.f, 0.f};
        float mold = -1e30f, lsum = 0.f;

        const int ntiles = 2 * qt + 2;
        for (int kt = 0; kt < ntiles; ++kt) {
            __syncthreads();   // prev tile's K/V reads done before overwrite
            // ---- stage K cols 0..63 from kv (packed) ----
            #pragma unroll
            for (int i = 0; i < 8; ++i) {
                const int idx = tid + i * 256;
                const int r = idx >> 6, c = idx & 63;
                const unsigned int u =
                    kv[(size_t)(rowK0 + kt * 32 + r) * 2048 + h * 64 + c];
                Kh[r * KS + c] = bfbits(u);
                Kl[r * KS + c] = bfbits(u >> 16);
            }
            // ---- stage K cols 64..95 from kr ----
            #pragma unroll
            for (int i = 0; i < 4; ++i) {
                const int idx = tid + i * 256;
                const int r = idx >> 5, c = idx & 31;
                const unsigned int u =
                    kr[(size_t)(rowK0 + kt * 32 + r) * 32 + c];
                Kh[r * KS + 64 + c] = bfbits(u);
                Kl[r * KS + 64 + c] = bfbits(u >> 16);
            }
            // ---- stage V^T (hi only) ----
            #pragma unroll
            for (int i = 0; i < 8; ++i) {
                const int idx = tid + i * 256;
                const int r = idx >> 6, c = idx & 63;
                const unsigned int u =
                    kv[(size_t)(rowK0 + kt * 32 + r) * 2048 + 1024 + h * 64 + c];
                Vth[c * VTS + r] = bfbits(u);
            }
            __syncthreads();

            // ---- S^T = K Q^T (3-term split); C/D: col=q(l15), row=kv ----
            f32x4 accS[2];
            accS[0] = (f32x4){0.f, 0.f, 0.f, 0.f};
            accS[1] = (f32x4){0.f, 0.f, 0.f, 0.f};
            #pragma unroll
            for (int jt = 0; jt < 2; ++jt) {
                #pragma unroll
                for (int kc = 0; kc < 3; ++kc) {
                    const int off = (jt * 16 + l15) * KS + kc * 32 + lg * 8;
                    const bf16x8 fKh = *(const bf16x8*)&Kh[off];
                    const bf16x8 fKl = *(const bf16x8*)&Kl[off];
                    accS[jt] = __builtin_amdgcn_mfma_f32_16x16x32_bf16(
                        fKl, fQh[kc], accS[jt], 0, 0, 0);
                    accS[jt] = __builtin_amdgcn_mfma_f32_16x16x32_bf16(
                        fKh, fQl[kc], accS[jt], 0, 0, 0);
                    accS[jt] = __builtin_amdgcn_mfma_f32_16x16x32_bf16(
                        fKh, fQh[kc], accS[jt], 0, 0, 0);
                }
            }

            // ---- scale + causal mask (lane owns q=qg; rows are kv) ----
            float sv[2][4];
            #pragma unroll
            for (int jt = 0; jt < 2; ++jt)
                #pragma unroll
                for (int r = 0; r < 4; ++r) sv[jt][r] = accS[jt][r] * scale;
            if (kt * 32 + 31 > qt * 64 + w * 16) {
                #pragma unroll
                for (int jt = 0; jt < 2; ++jt)
                    #pragma unroll
                    for (int r = 0; r < 4; ++r) {
                        const int kvg = kt * 32 + jt * 16 + lg * 4 + r;
                        if (kvg > qg) sv[jt][r] = -1e30f;
                    }
            }

            // ---- per-lane online softmax (2-shfl reduce over 4 dup lanes) --
            float m8 = sv[0][0];
            #pragma unroll
            for (int jt = 0; jt < 2; ++jt)
                #pragma unroll
                for (int r = 0; r < 4; ++r) m8 = fmaxf(m8, sv[jt][r]);
            m8 = fmaxf(m8, __shfl_xor(m8, 16, 64));
            m8 = fmaxf(m8, __shfl_xor(m8, 32, 64));
            const float mnew = fmaxf(mold, m8);
            const float rs = expf(mold - mnew);
            float psum = 0.f;
            float pv[2][4];
            #pragma unroll
            for (int jt = 0; jt < 2; ++jt)
                #pragma unroll
                for (int r = 0; r < 4; ++r) {
                    const float p = expf(sv[jt][r] - mnew);
                    pv[jt][r] = p;
                    psum += p;
                }
            psum += __shfl_xor(psum, 16, 64);
            psum += __shfl_xor(psum, 32, 64);
            lsum = lsum * rs + psum;
            mold = mnew;

            // ---- P -> LDS as P[q][kv] (wave-local) ----
            #pragma unroll
            for (int jt = 0; jt < 2; ++jt)
                #pragma unroll
                for (int r = 0; r < 4; ++r)
                    P[(w * 16 + l15) * PSTR + jt * 16 + lg * 4 + r] =
                        (__bf16)pv[jt][r];
            if (lane < 16) rsA[w * 16 + lane] = rs;
            const f32x4 rsv = *(const f32x4*)&rsA[w * 16 + lg * 4];

            // ---- rescale O, then PV: accO(col=d,row=q) += P x V^T ----
            #pragma unroll
            for (int jd = 0; jd < 4; ++jd)
                #pragma unroll
                for (int r = 0; r < 4; ++r) accO[jd][r] *= rsv[r];

            const bf16x8 fP = *(const bf16x8*)&P[(w * 16 + l15) * PSTR + lg * 8];
            #pragma unroll
            for (int jd = 0; jd < 4; ++jd) {
                const bf16x8 fV = *(const bf16x8*)&Vth[(jd * 16 + l15) * VTS + lg * 8];
                accO[jd] = __builtin_amdgcn_mfma_f32_16x16x32_bf16(
                    fP, fV, accO[jd], 0, 0, 0);
            }
        }

        // ---- epilogue: packed writes ----
        if (lane < 16) lsA[w * 16 + lane] = lsum;
        const f32x4 lsv = *(const f32x4*)&lsA[w * 16 + lg * 4];
        #pragma unroll
        for (int r = 0; r < 4; ++r) {
            const float linv = 1.0f / lsv[r];
            const int grow = rowQ0 + w * 16 + lg * 4 + r;
            #pragma unroll
            for (int jd = 0; jd < 4; ++jd)
                att[(size_t)grow * 1024 + h * 64 + jd * 16 + l15] =
                    packsplit(accO[jd][r] * linv);
        }
    }
}

static inline void gemm(hipStream_t s, const unsigned int* Ap, int lda,
                        const unsigned int* Bt, int ldb,
                        const float* bias, const float* res, int ldres,
                        float* Cf, unsigned int* Cp, int ldc,
                        int M, int N, int K, int act)
{
    dim3 grid((N + 127) / 128, M / 128);
    gemm_mfma_kernel<<<grid, 256, 0, s>>>(Ap, lda, Bt, ldb, bias, res, ldres,
                                          Cf, Cp, ldc, N, K, act);
}

static inline void tpack(hipStream_t s, const float* w, unsigned int* wt,
                         int K, int N)
{
    dim3 grid(K / 32, N / 32);
    transpose_pack_kernel<<<grid, 256, 0, s>>>(w, wt, N, K);
}

extern "C" void kernel_launch(void* const* d_in, const int* in_sizes, int n_in,
                              void* d_out, int out_size, void* d_ws, size_t ws_size,
                              hipStream_t stream)
{
    const float* x   = (const float*)d_in[0];
    const float* w1  = (const float*)d_in[1];
    const float* b1  = (const float*)d_in[2];
    const float* wkr = (const float*)d_in[3];
    const float* bkr = (const float*)d_in[4];
    const float* wqr = (const float*)d_in[5];
    const float* bqr = (const float*)d_in[6];
    const float* wkv = (const float*)d_in[7];
    const float* bkv = (const float*)d_in[8];
    const float* wq  = (const float*)d_in[9];
    const float* bq  = (const float*)d_in[10];
    const float* wo  = (const float*)d_in[11];
    const float* bo  = (const float*)d_in[12];
    const float* wi  = (const float*)d_in[13];
    const float* bi  = (const float*)d_in[14];
    const float* wo2 = (const float*)d_in[15];
    const float* bo2 = (const float*)d_in[16];
    const float* g1  = (const float*)d_in[17];
    const float* g2  = (const float*)d_in[18];
    float* out = (float*)d_out;
    float* ws  = (float*)d_ws;

    const size_t MF = (size_t)1 << 20;
    unsigned int* xnp  = (unsigned int*)ws;              // 4MF
    unsigned int* hbp  = (unsigned int*)(ws + 4 * MF);   // 4MF
    unsigned int* kvbp = (unsigned int*)(ws + 8 * MF);   // 8MF
    unsigned int* qbp  = (unsigned int*)(ws + 16 * MF);  // 4MF
    unsigned int* qrbp = (unsigned int*)(ws + 20 * MF);  // 2MF
    unsigned int* krbp = (unsigned int*)(ws + 22 * MF);  // 128K
    unsigned int* attbp = hbp;           // hb dead after q-GEMM
    unsigned int* ffhp  = hbp;           // spans 4MF..20MF, all dead by FFN
    // transposed packed weights (rows padded to multiple of 128)
    unsigned int* w1T  = (unsigned int*)(ws + 23 * MF);  // 1024x1024 = 1M
    unsigned int* wkrT = (unsigned int*)(ws + 24 * MF);  // 128x1024 pad = 128K
    unsigned int* wqrT = (unsigned int*)(ws + 25 * MF);  // 512x1024 = 512K
    unsigned int* wkvT = (unsigned int*)(ws + 26 * MF);  // 2048x512 = 1M
    unsigned int* wqT  = (unsigned int*)(ws + 27 * MF);  // 1024x512 = 512K
    unsigned int* woT  = (unsigned int*)(ws + 28 * MF);  // 1024x1024 = 1M
    unsigned int* wiT  = (unsigned int*)(ws + 29 * MF);  // 4096x1024 = 4M
    unsigned int* wo2T = (unsigned int*)(ws + 33 * MF);  // 1024x4096 = 4M -> 37MF

    // ---- weight transpose+split precompute ----
    tpack(stream, w1,  w1T,  1024, 1024);
    tpack(stream, wkr, wkrT, 1024, 32);
    tpack(stream, wqr, wqrT, 1024, 512);
    tpack(stream, wkv, wkvT, 512, 2048);
    tpack(stream, wq,  wqT,  512, 1024);
    tpack(stream, wo,  woT,  1024, 1024);
    tpack(stream, wi,  wiT,  1024, 4096);
    tpack(stream, wo2, wo2T, 4096, 1024);

    // ---- attention branch ----
    rmsnorm_kernel<<<4096, 256, 0, stream>>>(x, g1, xnp);
    gemm(stream, xnp, 1024, w1T, 1024, b1, nullptr, 0, nullptr, hbp, 1024,
         4096, 1024, 1024, 0);
    gemm(stream, hbp, 1024, wkrT, 1024, bkr, nullptr, 0, nullptr, krbp, 32,
         4096, 32, 1024, 0);
    gemm(stream, hbp, 1024, wqrT, 1024, bqr, nullptr, 0, nullptr, qrbp, 512,
         4096, 512, 1024, 0);
    gemm(stream, hbp, 1024, wkvT, 512, bkv, nullptr, 0, nullptr, kvbp, 2048,
         4096, 2048, 512, 0);
    gemm(stream, hbp + 512, 1024, wqT, 512, bq, nullptr, 0, nullptr, qbp, 1024,
         4096, 1024, 512, 0);
    rope_kernel<<<(4096 * 16 + 255) / 256, 256, 0, stream>>>(krbp, 32, 4096 * 16);
    rope_kernel<<<(4096 * 256 + 255) / 256, 256, 0, stream>>>(qrbp, 512, 4096 * 256);
    attn_mfma_kernel<<<dim3(16, 16, 2), 256, 0, stream>>>(qbp, qrbp, kvbp, krbp, attbp);
    gemm(stream, attbp, 1024, woT, 1024, bo, x, 1024, out, nullptr, 1024,
         4096, 1024, 1024, 0);

    // ---- FFN branch ----
    rmsnorm_kernel<<<4096, 256, 0, stream>>>(out, g2, xnp);
    gemm(stream, xnp, 1024, wiT, 1024, bi, nullptr, 0, nullptr, ffhp, 4096,
         4096, 4096, 1024, 1);
    gemm(stream, ffhp, 4096, wo2T, 4096, bo2, out, 1024, out, nullptr, 1024,
         4096, 1024, 4096, 0);
}